// Round 7
// baseline (7551.752 us; speedup 1.0000x reference)
//
#include <hip/hip_runtime.h>
#include <math.h>

#define BB 16
#define TT 16
#define KK 4
#define VV 10003
#define DD 256
#define CC 64
#define NTILE 40        // ceil(V/256) v-tiles
#define RPB 16          // rows per k_gemm block
#define VP 10016        // padded row stride for logits scratch
#define FNEG (-1e30f)

// ---------- top-4 list, f32 keys (tie-break: lower index wins) ----------
struct L4 { float v[4]; int ix[4]; };

__device__ __forceinline__ void l4_init(L4 &l) {
#pragma unroll
  for (int j = 0; j < 4; ++j) { l.v[j] = FNEG; l.ix[j] = 0x7fffffff; }
}
__device__ __forceinline__ bool better(float v, int ix, float v2, int ix2) {
  return (v > v2) || (v == v2 && ix < ix2);
}
__device__ __forceinline__ void l4_insert(L4 &l, float v, int ix) {
  if (!better(v, ix, l.v[3], l.ix[3])) return;
  int p = 3;
  while (p > 0 && better(v, ix, l.v[p-1], l.ix[p-1])) {
    l.v[p] = l.v[p-1]; l.ix[p] = l.ix[p-1]; --p;
  }
  l.v[p] = v; l.ix[p] = ix;
}

// ---------- numpy pairwise_sum, bit-exact replica (f32, contiguous) ----------
__device__ float np_block_sum(const float* a, int n) {   // 8 <= n <= 128
  float r0=a[0],r1=a[1],r2=a[2],r3=a[3],r4=a[4],r5=a[5],r6=a[6],r7=a[7];
  int i;
  for (i = 8; i + 8 <= n; i += 8) {
    r0 += a[i+0]; r1 += a[i+1]; r2 += a[i+2]; r3 += a[i+3];
    r4 += a[i+4]; r5 += a[i+5]; r6 += a[i+6]; r7 += a[i+7];
  }
  float res = ((r0 + r1) + (r2 + r3)) + ((r4 + r5) + (r6 + r7));
  for (; i < n; ++i) res += a[i];
  return res;
}
__device__ float np_pairwise(const float* a, int n) {
  if (n < 8) { float res = 0.f; for (int i = 0; i < n; ++i) res += a[i]; return res; }
  if (n <= 128) return np_block_sum(a, n);
  int n2 = (n / 2); n2 -= (n2 % 8);
  return np_pairwise(a, n2) + np_pairwise(a + n2, n - n2);
}

// ---------- kernel 0: init chain ----------
__global__ void k_init(const int* __restrict__ loc_tar, int* __restrict__ chainA) {
  int t = threadIdx.x;            // 256 = B*T
  int b = t >> 4, j = t & 15;
  chainA[t] = (j == 0) ? loc_tar[b * TT] : 0;
}

// ---------- kernel 1: sgemm-mimic logits -> global scratch ----------
// grid (NTILE, ceil(N/RPB)), 256 threads. Thread t owns column v = tile*256+t:
// Lg[n][v] = fmaf-chain_{d=0..255}(xs[r][d], Wv[d][v]) + bv[v]
__global__ __launch_bounds__(256)
void k_gemm(const float* __restrict__ E, const float* __restrict__ zs,
            const float* __restrict__ Wv, const float* __restrict__ bv,
            const int* __restrict__ chain, float* __restrict__ Lg,
            int step, int N, int Mshift) {
  __shared__ float xs[RPB * DD];     // 16 KB
  __shared__ int cs[RPB];

  const int t = threadIdx.x;
  const int tile = blockIdx.x;
  const int n0 = blockIdx.y * RPB;
  const int v = tile * 256 + t;
  const int vok = (v < VV);
  const int vc = vok ? v : (VV - 1);

  if (t < RPB) {
    int n = n0 + t;
    int c = (n < N) ? chain[n * TT + step] : 0;
    if ((unsigned)c >= VV) c = 0;    // defensive
    cs[t] = c;
  }
  __syncthreads();

  // stage xs rows: h = E[c] + zs[b]  (single f32 add, np order)
  for (int e = t; e < RPB * DD; e += 256) {
    int r = e >> 8, d = e & 255;
    int n = n0 + r;
    int b = (n < N) ? (n >> Mshift) : 0;
    xs[e] = E[cs[r] * DD + d] + zs[b * DD + d];
  }
  __syncthreads();

  float acc[RPB];
#pragma unroll
  for (int r = 0; r < RPB; ++r) acc[r] = 0.f;

  // sequential-k fused-FMA chain per (row, col) — mimics BLAS sgemm micro-kernel
  for (int d = 0; d < DD; ++d) {
    float w = Wv[d * VV + vc];
#pragma unroll
    for (int r = 0; r < RPB; ++r) acc[r] = fmaf(xs[r * DD + d], w, acc[r]);
  }

  if (vok) {
    const float bvv = bv[v];
#pragma unroll
    for (int r = 0; r < RPB; ++r) {
      int n = n0 + r;
      if (n < N) Lg[(size_t)n * VP + v] = acc[r] + bvv;   // bias after gemm (np)
    }
  }
}

// ---------- kernel 2: per-row np-exact max/top4, exp in place, pairwise lse ----
__global__ __launch_bounds__(256)
void k_red(float* __restrict__ Lg, float* __restrict__ topP,
           int* __restrict__ topI) {
  __shared__ float pm[256];
  __shared__ float pv4[256 * 4];
  __shared__ int   pi4[256 * 4];
  __shared__ float smax[1];

  const int n = blockIdx.x;
  const int t = threadIdx.x;
  float* row = Lg + (size_t)n * VP;

  // phase 1: per-thread exact max + top4 over v = t, t+256, ...
  float m = FNEG;
  L4 top; l4_init(top);
  for (int v = t; v < VV; v += 256) {
    float x = row[v];
    if (x > m) m = x;
    l4_insert(top, x, v);
  }
  pm[t] = m;
#pragma unroll
  for (int j = 0; j < 4; ++j) { pv4[t * 4 + j] = top.v[j]; pi4[t * 4 + j] = top.ix[j]; }
  __syncthreads();

  // thread 0: exact serial merge (max is order-free; top4 compares are exact)
  L4 g;
  if (t == 0) {
    float gm = pm[0];
    for (int u = 1; u < 256; ++u) if (pm[u] > gm) gm = pm[u];
    l4_init(g);
    for (int u = 0; u < 256; ++u)
#pragma unroll
      for (int j = 0; j < 4; ++j) l4_insert(g, pv4[u * 4 + j], pi4[u * 4 + j]);
    smax[0] = gm;
  }
  __syncthreads();

  // phase 2: e = exp(x - m) elementwise (f32 sub then exp), overwrite in place
  const float gm = smax[0];
  for (int v = t; v < VV; v += 256) {
    float sh = row[v] - gm;
    row[v] = (float)exp((double)sh);   // f64-emulated f32 exp (≈ np.exp)
  }
  __syncthreads();

  // thread 0: numpy-pairwise sum + finalize topP/topI
  if (t == 0) {
    float s  = np_pairwise(row, VV);
    float ls = (float)log((double)s);
#pragma unroll
    for (int j = 0; j < 4; ++j) {
      topP[n * 4 + j] = (g.v[j] - gm) - ls;   // (x - m) - log(s), two f32 subs
      topI[n * 4 + j] = g.ix[j];
    }
  }
}

// ---------- kernel 3: beam update (pure f32 products, stable descending) ----------
__global__ __launch_bounds__(64)
void k_beam(const float* __restrict__ topP, const int* __restrict__ topI,
            float* __restrict__ prob, const int* __restrict__ chain_cur,
            int* __restrict__ chain_next, int step) {
  int b = threadIdx.x;
  if (b >= BB) return;
  if (step == 0) {
    for (int k = 0; k < 4; ++k) {
      int dst = b * 4 + k;
      for (int j = 0; j < TT; ++j) chain_next[dst * TT + j] = chain_cur[b * TT + j];
      int tok = topI[b * 4 + k]; if ((unsigned)tok >= VV) tok = 0;
      chain_next[dst * TT + 1] = tok;
      prob[b * 8 + k] = topP[b * 4 + k];
    }
  } else {
    const int M = (step == 1) ? 4 : 8;
    float pr[8];
    for (int m = 0; m < M; ++m) pr[m] = prob[b * 8 + m];
    float cand[32];
    const int nc = M * 4;
    for (int m = 0; m < M; ++m)
      for (int k = 0; k < 4; ++k)
        cand[m * 4 + k] = pr[m] * topP[(b * M + m) * 4 + k];  // f32 product (faithful)
    bool used[32];
    for (int c = 0; c < nc; ++c) used[c] = false;
    float np_[8];
    for (int j = 0; j < 8; ++j) {
      int best = -1; float bvv = 0.f;
      for (int c = 0; c < nc; ++c)
        if (!used[c] && (best < 0 || cand[c] > bvv)) { best = c; bvv = cand[c]; }
      used[best] = true; np_[j] = bvv;
      int mm = best >> 2, kk = best & 3;
      int src = b * M + mm, dst = b * 8 + j;
      for (int q = 0; q < TT; ++q) chain_next[dst * TT + q] = chain_cur[src * TT + q];
      int tok = topI[src * 4 + kk]; if ((unsigned)tok >= VV) tok = 0;
      chain_next[dst * TT + step + 1] = tok;
    }
    for (int j = 0; j < 8; ++j) prob[b * 8 + j] = np_[j];
  }
}

// ---------- kernel 4: finalize: loc_chain + tim_chain ----------
__global__ __launch_bounds__(64)
void k_final(const int* __restrict__ chain, const float* __restrict__ E,
             const float* __restrict__ Wc, const float* __restrict__ bc,
             const float* __restrict__ Wt, const float* __restrict__ zt,
             const float* __restrict__ Wzt, float* __restrict__ out) {
  int blk = blockIdx.x;           // 224 = B*(T-2)
  int b = blk / (TT - 2), t = blk % (TT - 2);
  int lane = threadIdx.x;         // 64 = C
  int loc = chain[(b * 8) * TT + 1 + t];   // best beam, positions 1..T-2
  if ((unsigned)loc >= VV) loc = 0;        // defensive
  double acc = (double)bc[lane];
  const float* er = E + loc * DD;
  for (int d = 0; d < DD; ++d) acc += (double)er[d] * (double)Wc[d * CC + lane];
  double val = tanh(acc) * (double)Wt[lane];
  const float* ztr = zt + b * DD;
#pragma unroll
  for (int q = 0; q < 4; ++q) val += (double)ztr[lane * 4 + q] * (double)Wzt[lane * 4 + q];
  for (int off = 32; off; off >>= 1) val += __shfl_down(val, off);
  if (lane == 0) {
    out[b * (TT - 2) + t] = (float)loc;                 // loc_chain as float
    out[BB * (TT - 2) + b * (TT - 2) + t] = (float)val; // tim_chain
  }
}

// ---------- host ----------
extern "C" void kernel_launch(void* const* d_in, const int* in_sizes, int n_in,
                              void* d_out, int out_size, void* d_ws, size_t ws_size,
                              hipStream_t stream) {
  const int*   loc_tar = (const int*)  d_in[0];
  const float* zs      = (const float*)d_in[1];
  const float* zt      = (const float*)d_in[2];
  const float* E       = (const float*)d_in[3];
  const float* Wv      = (const float*)d_in[4];
  const float* bv      = (const float*)d_in[5];
  const float* Wc      = (const float*)d_in[6];
  const float* bc      = (const float*)d_in[7];
  const float* Wt      = (const float*)d_in[8];
  const float* Wzt     = (const float*)d_in[9];
  float* out = (float*)d_out;

  char* w = (char*)d_ws;
  float* Lg     = (float*)(w);                   // 128*10016*4 = 5,128,192 B
  float* topP   = (float*)(w + 5128192);         // 512 f32 = 2048 B
  int*   topI   = (int*)  (w + 5130240);         // 512 int = 2048 B
  float* prob   = (float*)(w + 5132288);         // 128 f32 = 512 B
  int*   chainA = (int*)  (w + 5132800);         // 2048 int = 8192 B
  int*   chainB = (int*)  (w + 5140992);         // 2048 int = 8192 B

  k_init<<<1, 256, 0, stream>>>(loc_tar, chainA);

  int N = BB;
  int* cur = chainA;
  int* nxt = chainB;
  for (int i = 0; i < TT - 1; ++i) {
    int Mshift = (i == 0) ? 0 : ((i == 1) ? 2 : 3);
    dim3 g1(NTILE, (N + RPB - 1) / RPB);
    k_gemm<<<g1, 256, 0, stream>>>(E, zs, Wv, bv, cur, Lg, i, N, Mshift);
    k_red<<<N, 256, 0, stream>>>(Lg, topP, topI);
    k_beam<<<1, 64, 0, stream>>>(topP, topI, prob, cur, nxt, i);
    int* t2 = cur; cur = nxt; nxt = t2;
    N = (i == 0) ? BB * KK : BB * 2 * KK;
  }

  k_final<<<BB * (TT - 2), 64, 0, stream>>>(cur, E, Wc, bc, Wt, zt, Wzt, out);
}

// Round 8
// 5054.178 us; speedup vs baseline: 1.4942x; 1.4942x over previous
//
#include <hip/hip_runtime.h>
#include <math.h>

#define BB 16
#define TT 16
#define KK 4
#define VV 10003
#define DD 256
#define CC 64
#define NTILE 40        // ceil(V/256) v-tiles
#define RPB 16          // rows per k_gemm block
#define VP 10016        // padded row stride for logits scratch
#define MAXLEAF 192
#define FNEG (-1e30f)

// ---------- top-4 list, f32 keys (tie-break: lower index wins) ----------
struct L4 { float v[4]; int ix[4]; };

__device__ __forceinline__ void l4_init(L4 &l) {
#pragma unroll
  for (int j = 0; j < 4; ++j) { l.v[j] = FNEG; l.ix[j] = 0x7fffffff; }
}
__device__ __forceinline__ bool better(float v, int ix, float v2, int ix2) {
  return (v > v2) || (v == v2 && ix < ix2);
}
__device__ __forceinline__ void l4_insert(L4 &l, float v, int ix) {
  if (!better(v, ix, l.v[3], l.ix[3])) return;
  int p = 3;
  while (p > 0 && better(v, ix, l.v[p-1], l.ix[p-1])) {
    l.v[p] = l.v[p-1]; l.ix[p] = l.ix[p-1]; --p;
  }
  l.v[p] = v; l.ix[p] = ix;
}
__device__ __forceinline__ void l4_merge(L4 &a, const L4 &b) {
  L4 r; int ia = 0, ib = 0;
#pragma unroll
  for (int j = 0; j < 4; ++j) {
    if (better(a.v[ia], a.ix[ia], b.v[ib], b.ix[ib])) {
      r.v[j] = a.v[ia]; r.ix[j] = a.ix[ia]; ++ia;
    } else {
      r.v[j] = b.v[ib]; r.ix[j] = b.ix[ib]; ++ib;
    }
  }
  a = r;
}

// ---------- numpy pairwise_sum replica, parallel-leaf version ----------
// 8-accumulator block sum (numpy base case, 8 <= n <= 128) — bit-exact
__device__ float np_block_sum(const float* a, int n) {
  float r0=a[0],r1=a[1],r2=a[2],r3=a[3],r4=a[4],r5=a[5],r6=a[6],r7=a[7];
  int i;
  for (i = 8; i + 8 <= n; i += 8) {
    r0 += a[i+0]; r1 += a[i+1]; r2 += a[i+2]; r3 += a[i+3];
    r4 += a[i+4]; r5 += a[i+5]; r6 += a[i+6]; r7 += a[i+7];
  }
  float res = ((r0 + r1) + (r2 + r3)) + ((r4 + r5) + (r6 + r7));
  for (; i < n; ++i) res += a[i];
  return res;
}
// enumerate recursion leaves left-to-right (same splits as numpy pairwise)
__device__ int np_leaves(int base, int n, short* st, short* ln, int cnt) {
  if (n <= 128) { st[cnt] = (short)base; ln[cnt] = (short)n; return cnt + 1; }
  int n2 = n / 2; n2 -= n2 % 8;
  cnt = np_leaves(base, n2, st, ln, cnt);
  return np_leaves(base + n2, n - n2, st, ln, cnt);
}
// replay the recursion combines over precomputed leaf sums (identical order)
__device__ float np_replay(int n, const float* leafsum, int* idx) {
  if (n <= 128) return leafsum[(*idx)++];
  int n2 = n / 2; n2 -= n2 % 8;
  float l = np_replay(n2, leafsum, idx);
  float r = np_replay(n - n2, leafsum, idx);
  return l + r;
}

// ---------- kernel 0: init chain ----------
__global__ void k_init(const int* __restrict__ loc_tar, int* __restrict__ chainA) {
  int t = threadIdx.x;            // 256 = B*T
  int b = t >> 4, j = t & 15;
  chainA[t] = (j == 0) ? loc_tar[b * TT] : 0;
}

// ---------- kernel 1: sgemm-mimic logits -> global scratch (UNCHANGED R7) ------
__global__ __launch_bounds__(256)
void k_gemm(const float* __restrict__ E, const float* __restrict__ zs,
            const float* __restrict__ Wv, const float* __restrict__ bv,
            const int* __restrict__ chain, float* __restrict__ Lg,
            int step, int N, int Mshift) {
  __shared__ float xs[RPB * DD];     // 16 KB
  __shared__ int cs[RPB];

  const int t = threadIdx.x;
  const int tile = blockIdx.x;
  const int n0 = blockIdx.y * RPB;
  const int v = tile * 256 + t;
  const int vok = (v < VV);
  const int vc = vok ? v : (VV - 1);

  if (t < RPB) {
    int n = n0 + t;
    int c = (n < N) ? chain[n * TT + step] : 0;
    if ((unsigned)c >= VV) c = 0;    // defensive
    cs[t] = c;
  }
  __syncthreads();

  // stage xs rows: h = E[c] + zs[b]  (single f32 add, np order)
  for (int e = t; e < RPB * DD; e += 256) {
    int r = e >> 8, d = e & 255;
    int n = n0 + r;
    int b = (n < N) ? (n >> Mshift) : 0;
    xs[e] = E[cs[r] * DD + d] + zs[b * DD + d];
  }
  __syncthreads();

  float acc[RPB];
#pragma unroll
  for (int r = 0; r < RPB; ++r) acc[r] = 0.f;

  // sequential-k fused-FMA chain per (row, col) — mimics BLAS sgemm micro-kernel
  for (int d = 0; d < DD; ++d) {
    float w = Wv[d * VV + vc];
#pragma unroll
    for (int r = 0; r < RPB; ++r) acc[r] = fmaf(xs[r * DD + d], w, acc[r]);
  }

  if (vok) {
    const float bvv = bv[v];
#pragma unroll
    for (int r = 0; r < RPB; ++r) {
      int n = n0 + r;
      if (n < N) Lg[(size_t)n * VP + v] = acc[r] + bvv;   // bias after gemm (np)
    }
  }
}

// ---------- kernel 2: per-row np-exact max/top4/pairwise-lse, parallelized -----
// Identical arithmetic to R7's serial version; only execution order of
// order-independent ops (max, top4-set) and leaf-parallel pairwise changed.
__global__ __launch_bounds__(256)
void k_red(const float* __restrict__ Lg, float* __restrict__ topP,
           int* __restrict__ topI) {
  __shared__ float row[VV];          // 40012 B (logits, then exp'd values)
  __shared__ float pm[256];          // 1 KB
  __shared__ float pv4[256 * 4];     // 4 KB
  __shared__ int   pi4[256 * 4];     // 4 KB
  __shared__ float leafsum[MAXLEAF]; // 768 B
  __shared__ short lstart[MAXLEAF];  // 384 B
  __shared__ short llen[MAXLEAF];    // 384 B
  __shared__ int   nleaf;

  const int n = blockIdx.x;
  const int t = threadIdx.x;
  const float* grow = Lg + (size_t)n * VP;

  // coalesced load of the logit row into LDS
  for (int v = t; v < VV; v += 256) row[v] = grow[v];
  if (t == 0) nleaf = np_leaves(0, VV, lstart, llen, 0);
  __syncthreads();

  // per-thread exact max + top4 over v = t, t+256, ... (ascending)
  float m = FNEG;
  L4 top; l4_init(top);
  for (int v = t; v < VV; v += 256) {
    float x = row[v];
    if (x > m) m = x;
    l4_insert(top, x, v);
  }
  pm[t] = m;
#pragma unroll
  for (int j = 0; j < 4; ++j) { pv4[t * 4 + j] = top.v[j]; pi4[t * 4 + j] = top.ix[j]; }
  __syncthreads();

  // exact tree reduce (max + top4 set selection are order-independent)
  for (int str = 128; str >= 1; str >>= 1) {
    if (t < str) {
      if (pm[t + str] > pm[t]) pm[t] = pm[t + str];
      L4 a, b;
#pragma unroll
      for (int j = 0; j < 4; ++j) {
        a.v[j] = pv4[t * 4 + j];          a.ix[j] = pi4[t * 4 + j];
        b.v[j] = pv4[(t + str) * 4 + j];  b.ix[j] = pi4[(t + str) * 4 + j];
      }
      l4_merge(a, b);
#pragma unroll
      for (int j = 0; j < 4; ++j) { pv4[t * 4 + j] = a.v[j]; pi4[t * 4 + j] = a.ix[j]; }
    }
    __syncthreads();
  }
  const float gm = pm[0];

  // e = exp(x - m): f32 sub then f64-emulated f32 exp (same as R7), in LDS
  for (int v = t; v < VV; v += 256)
    row[v] = (float)exp((double)(row[v] - gm));
  __syncthreads();

  // parallel leaf block-sums (numpy 8-accumulator base case, bit-exact)
  if (t < nleaf) leafsum[t] = np_block_sum(&row[lstart[t]], llen[t]);
  __syncthreads();

  // thread 0: replay recursion combines (identical association), finalize
  if (t == 0) {
    int idx = 0;
    float s  = np_replay(VV, leafsum, &idx);
    float ls = (float)log((double)s);
#pragma unroll
    for (int j = 0; j < 4; ++j) {
      topP[n * 4 + j] = (pv4[j] - gm) - ls;   // (x - m) - log(s), two f32 subs
      topI[n * 4 + j] = pi4[j];
    }
  }
}

// ---------- kernel 3: beam update (UNCHANGED R7) ----------
__global__ __launch_bounds__(64)
void k_beam(const float* __restrict__ topP, const int* __restrict__ topI,
            float* __restrict__ prob, const int* __restrict__ chain_cur,
            int* __restrict__ chain_next, int step) {
  int b = threadIdx.x;
  if (b >= BB) return;
  if (step == 0) {
    for (int k = 0; k < 4; ++k) {
      int dst = b * 4 + k;
      for (int j = 0; j < TT; ++j) chain_next[dst * TT + j] = chain_cur[b * TT + j];
      int tok = topI[b * 4 + k]; if ((unsigned)tok >= VV) tok = 0;
      chain_next[dst * TT + 1] = tok;
      prob[b * 8 + k] = topP[b * 4 + k];
    }
  } else {
    const int M = (step == 1) ? 4 : 8;
    float pr[8];
    for (int m = 0; m < M; ++m) pr[m] = prob[b * 8 + m];
    float cand[32];
    const int nc = M * 4;
    for (int m = 0; m < M; ++m)
      for (int k = 0; k < 4; ++k)
        cand[m * 4 + k] = pr[m] * topP[(b * M + m) * 4 + k];  // f32 product (faithful)
    bool used[32];
    for (int c = 0; c < nc; ++c) used[c] = false;
    float np_[8];
    for (int j = 0; j < 8; ++j) {
      int best = -1; float bvv = 0.f;
      for (int c = 0; c < nc; ++c)
        if (!used[c] && (best < 0 || cand[c] > bvv)) { best = c; bvv = cand[c]; }
      used[best] = true; np_[j] = bvv;
      int mm = best >> 2, kk = best & 3;
      int src = b * M + mm, dst = b * 8 + j;
      for (int q = 0; q < TT; ++q) chain_next[dst * TT + q] = chain_cur[src * TT + q];
      int tok = topI[src * 4 + kk]; if ((unsigned)tok >= VV) tok = 0;
      chain_next[dst * TT + step + 1] = tok;
    }
    for (int j = 0; j < 8; ++j) prob[b * 8 + j] = np_[j];
  }
}

// ---------- kernel 4: finalize: loc_chain + tim_chain (UNCHANGED R7) ----------
__global__ __launch_bounds__(64)
void k_final(const int* __restrict__ chain, const float* __restrict__ E,
             const float* __restrict__ Wc, const float* __restrict__ bc,
             const float* __restrict__ Wt, const float* __restrict__ zt,
             const float* __restrict__ Wzt, float* __restrict__ out) {
  int blk = blockIdx.x;           // 224 = B*(T-2)
  int b = blk / (TT - 2), t = blk % (TT - 2);
  int lane = threadIdx.x;         // 64 = C
  int loc = chain[(b * 8) * TT + 1 + t];   // best beam, positions 1..T-2
  if ((unsigned)loc >= VV) loc = 0;        // defensive
  double acc = (double)bc[lane];
  const float* er = E + loc * DD;
  for (int d = 0; d < DD; ++d) acc += (double)er[d] * (double)Wc[d * CC + lane];
  double val = tanh(acc) * (double)Wt[lane];
  const float* ztr = zt + b * DD;
#pragma unroll
  for (int q = 0; q < 4; ++q) val += (double)ztr[lane * 4 + q] * (double)Wzt[lane * 4 + q];
  for (int off = 32; off; off >>= 1) val += __shfl_down(val, off);
  if (lane == 0) {
    out[b * (TT - 2) + t] = (float)loc;                 // loc_chain as float
    out[BB * (TT - 2) + b * (TT - 2) + t] = (float)val; // tim_chain
  }
}

// ---------- host ----------
extern "C" void kernel_launch(void* const* d_in, const int* in_sizes, int n_in,
                              void* d_out, int out_size, void* d_ws, size_t ws_size,
                              hipStream_t stream) {
  const int*   loc_tar = (const int*)  d_in[0];
  const float* zs      = (const float*)d_in[1];
  const float* zt      = (const float*)d_in[2];
  const float* E       = (const float*)d_in[3];
  const float* Wv      = (const float*)d_in[4];
  const float* bv      = (const float*)d_in[5];
  const float* Wc      = (const float*)d_in[6];
  const float* bc      = (const float*)d_in[7];
  const float* Wt      = (const float*)d_in[8];
  const float* Wzt     = (const float*)d_in[9];
  float* out = (float*)d_out;

  char* w = (char*)d_ws;
  float* Lg     = (float*)(w);                   // 128*10016*4 = 5,128,192 B
  float* topP   = (float*)(w + 5128192);         // 512 f32 = 2048 B
  int*   topI   = (int*)  (w + 5130240);         // 512 int = 2048 B
  float* prob   = (float*)(w + 5132288);         // 128 f32 = 512 B
  int*   chainA = (int*)  (w + 5132800);         // 2048 int = 8192 B
  int*   chainB = (int*)  (w + 5140992);         // 2048 int = 8192 B

  k_init<<<1, 256, 0, stream>>>(loc_tar, chainA);

  int N = BB;
  int* cur = chainA;
  int* nxt = chainB;
  for (int i = 0; i < TT - 1; ++i) {
    int Mshift = (i == 0) ? 0 : ((i == 1) ? 2 : 3);
    dim3 g1(NTILE, (N + RPB - 1) / RPB);
    k_gemm<<<g1, 256, 0, stream>>>(E, zs, Wv, bv, cur, Lg, i, N, Mshift);
    k_red<<<N, 256, 0, stream>>>(Lg, topP, topI);
    k_beam<<<1, 64, 0, stream>>>(topP, topI, prob, cur, nxt, i);
    int* t2 = cur; cur = nxt; nxt = t2;
    N = (i == 0) ? BB * KK : BB * 2 * KK;
  }

  k_final<<<BB * (TT - 2), 64, 0, stream>>>(cur, E, Wc, bc, Wt, zt, Wzt, out);
}

// Round 9
// 4139.067 us; speedup vs baseline: 1.8245x; 1.2211x over previous
//
#include <hip/hip_runtime.h>
#include <math.h>

#define BB 16
#define TT 16
#define KK 4
#define VV 10003
#define DD 256
#define CC 64
#define NTILE 40        // ceil(V/256) v-tiles
#define RPB 16          // rows per k_gemm block
#define VP 10016        // padded row stride for logits scratch
#define MAXLEAF 192
#define MAXDEPTH 16
#define FNEG (-1e30f)

// ---------- top-4 list, f32 keys (tie-break: lower index wins) ----------
struct L4 { float v[4]; int ix[4]; };

__device__ __forceinline__ void l4_init(L4 &l) {
#pragma unroll
  for (int j = 0; j < 4; ++j) { l.v[j] = FNEG; l.ix[j] = 0x7fffffff; }
}
__device__ __forceinline__ bool better(float v, int ix, float v2, int ix2) {
  return (v > v2) || (v == v2 && ix < ix2);
}
__device__ __forceinline__ void l4_insert(L4 &l, float v, int ix) {
  if (!better(v, ix, l.v[3], l.ix[3])) return;
  int p = 3;
  while (p > 0 && better(v, ix, l.v[p-1], l.ix[p-1])) {
    l.v[p] = l.v[p-1]; l.ix[p] = l.ix[p-1]; --p;
  }
  l.v[p] = v; l.ix[p] = ix;
}
__device__ __forceinline__ void l4_merge(L4 &a, const L4 &b) {
  L4 r; int ia = 0, ib = 0;
#pragma unroll
  for (int j = 0; j < 4; ++j) {
    if (better(a.v[ia], a.ix[ia], b.v[ib], b.ix[ib])) {
      r.v[j] = a.v[ia]; r.ix[j] = a.ix[ia]; ++ia;
    } else {
      r.v[j] = b.v[ib]; r.ix[j] = b.ix[ib]; ++ib;
    }
  }
  a = r;
}

// ---------- numpy pairwise_sum replica ----------
// 8-accumulator block sum (numpy base case, 8 <= n <= 128) — bit-exact
__device__ float np_block_sum(const float* a, int n) {
  float r0=a[0],r1=a[1],r2=a[2],r3=a[3],r4=a[4],r5=a[5],r6=a[6],r7=a[7];
  int i;
  for (i = 8; i + 8 <= n; i += 8) {
    r0 += a[i+0]; r1 += a[i+1]; r2 += a[i+2]; r3 += a[i+3];
    r4 += a[i+4]; r5 += a[i+5]; r6 += a[i+6]; r7 += a[i+7];
  }
  float res = ((r0 + r1) + (r2 + r3)) + ((r4 + r5) + (r6 + r7));
  for (; i < n; ++i) res += a[i];
  return res;
}

// ---------- kernel 0: init chain ----------
__global__ void k_init(const int* __restrict__ loc_tar, int* __restrict__ chainA) {
  int t = threadIdx.x;            // 256 = B*T
  int b = t >> 4, j = t & 15;
  chainA[t] = (j == 0) ? loc_tar[b * TT] : 0;
}

// ---------- kernel 1: sgemm-mimic logits -> global scratch (UNCHANGED) --------
__global__ __launch_bounds__(256)
void k_gemm(const float* __restrict__ E, const float* __restrict__ zs,
            const float* __restrict__ Wv, const float* __restrict__ bv,
            const int* __restrict__ chain, float* __restrict__ Lg,
            int step, int N, int Mshift) {
  __shared__ float xs[RPB * DD];     // 16 KB
  __shared__ int cs[RPB];

  const int t = threadIdx.x;
  const int tile = blockIdx.x;
  const int n0 = blockIdx.y * RPB;
  const int v = tile * 256 + t;
  const int vok = (v < VV);
  const int vc = vok ? v : (VV - 1);

  if (t < RPB) {
    int n = n0 + t;
    int c = (n < N) ? chain[n * TT + step] : 0;
    if ((unsigned)c >= VV) c = 0;    // defensive
    cs[t] = c;
  }
  __syncthreads();

  // stage xs rows: h = E[c] + zs[b]  (single f32 add, np order)
  for (int e = t; e < RPB * DD; e += 256) {
    int r = e >> 8, d = e & 255;
    int n = n0 + r;
    int b = (n < N) ? (n >> Mshift) : 0;
    xs[e] = E[cs[r] * DD + d] + zs[b * DD + d];
  }
  __syncthreads();

  float acc[RPB];
#pragma unroll
  for (int r = 0; r < RPB; ++r) acc[r] = 0.f;

  // sequential-k fused-FMA chain per (row, col) — mimics BLAS sgemm micro-kernel
  for (int d = 0; d < DD; ++d) {
    float w = Wv[d * VV + vc];
#pragma unroll
    for (int r = 0; r < RPB; ++r) acc[r] = fmaf(xs[r * DD + d], w, acc[r]);
  }

  if (vok) {
    const float bvv = bv[v];
#pragma unroll
    for (int r = 0; r < RPB; ++r) {
      int n = n0 + r;
      if (n < N) Lg[(size_t)n * VP + v] = acc[r] + bvv;   // bias after gemm (np)
    }
  }
}

// ---------- kernel 2: per-row np-exact max/top4/pairwise-lse ------------------
// Same arithmetic as R8; recursion replaced by iterative LDS-stack traversal
// (identical DFS order => identical f32 add association).
__global__ __launch_bounds__(256)
void k_red(const float* __restrict__ Lg, float* __restrict__ topP,
           int* __restrict__ topI) {
  __shared__ float row[VV];          // 40012 B (logits, then exp'd values)
  __shared__ float pm[256];          // 1 KB
  __shared__ float pv4[256 * 4];     // 4 KB
  __shared__ int   pi4[256 * 4];     // 4 KB
  __shared__ float leafsum[MAXLEAF]; // 768 B
  __shared__ int   lstart[MAXLEAF];
  __shared__ int   llen[MAXLEAF];
  __shared__ int   nleaf;
  __shared__ int   stkA[MAXDEPTH];   // iterative-traversal stacks (thread 0)
  __shared__ int   stkB[MAXDEPTH];
  __shared__ float stkV[MAXDEPTH];
  __shared__ char  stkS[MAXDEPTH];

  const int n = blockIdx.x;
  const int t = threadIdx.x;
  const float* grow = Lg + (size_t)n * VP;

  // coalesced load of the logit row into LDS
  for (int v = t; v < VV; v += 256) row[v] = grow[v];

  // thread 0: enumerate numpy-pairwise leaves (iterative DFS, left-first)
  if (t == 0) {
    int sp = 0, cnt = 0, base = 0, nc = VV;
    for (;;) {
      while (nc > 128) {
        int n2 = nc / 2; n2 -= n2 % 8;
        stkA[sp] = base + n2; stkB[sp] = nc - n2; ++sp;   // push right subtree
        nc = n2;                                          // descend left
      }
      lstart[cnt] = base; llen[cnt] = nc; ++cnt;          // leaf
      if (sp == 0) break;
      --sp; base = stkA[sp]; nc = stkB[sp];               // pop next right
    }
    nleaf = cnt;
  }
  __syncthreads();

  // per-thread exact max + top4 over v = t, t+256, ... (ascending)
  float m = FNEG;
  L4 top; l4_init(top);
  for (int v = t; v < VV; v += 256) {
    float x = row[v];
    if (x > m) m = x;
    l4_insert(top, x, v);
  }
  pm[t] = m;
#pragma unroll
  for (int j = 0; j < 4; ++j) { pv4[t * 4 + j] = top.v[j]; pi4[t * 4 + j] = top.ix[j]; }
  __syncthreads();

  // exact tree reduce (max + top4 set selection are order-independent)
  for (int str = 128; str >= 1; str >>= 1) {
    if (t < str) {
      if (pm[t + str] > pm[t]) pm[t] = pm[t + str];
      L4 a, b;
#pragma unroll
      for (int j = 0; j < 4; ++j) {
        a.v[j] = pv4[t * 4 + j];          a.ix[j] = pi4[t * 4 + j];
        b.v[j] = pv4[(t + str) * 4 + j];  b.ix[j] = pi4[(t + str) * 4 + j];
      }
      l4_merge(a, b);
#pragma unroll
      for (int j = 0; j < 4; ++j) { pv4[t * 4 + j] = a.v[j]; pi4[t * 4 + j] = a.ix[j]; }
    }
    __syncthreads();
  }
  const float gm = pm[0];

  // e = exp(x - m): f32 sub then f64-emulated f32 exp (same as R7/R8), in LDS
  for (int v = t; v < VV; v += 256)
    row[v] = (float)exp((double)(row[v] - gm));
  __syncthreads();

  // parallel leaf block-sums (numpy 8-accumulator base case, bit-exact)
  if (t < nleaf) leafsum[t] = np_block_sum(&row[lstart[t]], llen[t]);
  __syncthreads();

  // thread 0: iterative replay of recursion combines (identical association)
  if (t == 0) {
    int sp = 0, idx = 0, nc = VV;
    float resv;
    for (;;) {
      while (nc > 128) {
        int n2 = nc / 2; n2 -= n2 % 8;
        stkB[sp] = nc - n2; stkS[sp] = 0; ++sp;   // frame: right size, stage 0
        nc = n2;                                  // descend left
      }
      float val = leafsum[idx++];                 // leaf value
      while (sp > 0 && stkS[sp - 1] == 1) {       // unwind completed frames
        val = stkV[sp - 1] + val;                 // left + right (np order)
        --sp;
      }
      if (sp == 0) { resv = val; break; }
      stkV[sp - 1] = val; stkS[sp - 1] = 1;       // save left, descend right
      nc = stkB[sp - 1];
    }
    float ls = (float)log((double)resv);
#pragma unroll
    for (int j = 0; j < 4; ++j) {
      topP[n * 4 + j] = (pv4[j] - gm) - ls;   // (x - m) - log(s), two f32 subs
      topI[n * 4 + j] = pi4[j];
    }
  }
}

// ---------- kernel 3: beam update (UNCHANGED) ----------
__global__ __launch_bounds__(64)
void k_beam(const float* __restrict__ topP, const int* __restrict__ topI,
            float* __restrict__ prob, const int* __restrict__ chain_cur,
            int* __restrict__ chain_next, int step) {
  int b = threadIdx.x;
  if (b >= BB) return;
  if (step == 0) {
    for (int k = 0; k < 4; ++k) {
      int dst = b * 4 + k;
      for (int j = 0; j < TT; ++j) chain_next[dst * TT + j] = chain_cur[b * TT + j];
      int tok = topI[b * 4 + k]; if ((unsigned)tok >= VV) tok = 0;
      chain_next[dst * TT + 1] = tok;
      prob[b * 8 + k] = topP[b * 4 + k];
    }
  } else {
    const int M = (step == 1) ? 4 : 8;
    float pr[8];
    for (int m = 0; m < M; ++m) pr[m] = prob[b * 8 + m];
    float cand[32];
    const int nc = M * 4;
    for (int m = 0; m < M; ++m)
      for (int k = 0; k < 4; ++k)
        cand[m * 4 + k] = pr[m] * topP[(b * M + m) * 4 + k];  // f32 product (faithful)
    bool used[32];
    for (int c = 0; c < nc; ++c) used[c] = false;
    float np_[8];
    for (int j = 0; j < 8; ++j) {
      int best = -1; float bvv = 0.f;
      for (int c = 0; c < nc; ++c)
        if (!used[c] && (best < 0 || cand[c] > bvv)) { best = c; bvv = cand[c]; }
      used[best] = true; np_[j] = bvv;
      int mm = best >> 2, kk = best & 3;
      int src = b * M + mm, dst = b * 8 + j;
      for (int q = 0; q < TT; ++q) chain_next[dst * TT + q] = chain_cur[src * TT + q];
      int tok = topI[src * 4 + kk]; if ((unsigned)tok >= VV) tok = 0;
      chain_next[dst * TT + step + 1] = tok;
    }
    for (int j = 0; j < 8; ++j) prob[b * 8 + j] = np_[j];
  }
}

// ---------- kernel 4: finalize: loc_chain + tim_chain (UNCHANGED) ----------
__global__ __launch_bounds__(64)
void k_final(const int* __restrict__ chain, const float* __restrict__ E,
             const float* __restrict__ Wc, const float* __restrict__ bc,
             const float* __restrict__ Wt, const float* __restrict__ zt,
             const float* __restrict__ Wzt, float* __restrict__ out) {
  int blk = blockIdx.x;           // 224 = B*(T-2)
  int b = blk / (TT - 2), t = blk % (TT - 2);
  int lane = threadIdx.x;         // 64 = C
  int loc = chain[(b * 8) * TT + 1 + t];   // best beam, positions 1..T-2
  if ((unsigned)loc >= VV) loc = 0;        // defensive
  double acc = (double)bc[lane];
  const float* er = E + loc * DD;
  for (int d = 0; d < DD; ++d) acc += (double)er[d] * (double)Wc[d * CC + lane];
  double val = tanh(acc) * (double)Wt[lane];
  const float* ztr = zt + b * DD;
#pragma unroll
  for (int q = 0; q < 4; ++q) val += (double)ztr[lane * 4 + q] * (double)Wzt[lane * 4 + q];
  for (int off = 32; off; off >>= 1) val += __shfl_down(val, off);
  if (lane == 0) {
    out[b * (TT - 2) + t] = (float)loc;                 // loc_chain as float
    out[BB * (TT - 2) + b * (TT - 2) + t] = (float)val; // tim_chain
  }
}

// ---------- host ----------
extern "C" void kernel_launch(void* const* d_in, const int* in_sizes, int n_in,
                              void* d_out, int out_size, void* d_ws, size_t ws_size,
                              hipStream_t stream) {
  const int*   loc_tar = (const int*)  d_in[0];
  const float* zs      = (const float*)d_in[1];
  const float* zt      = (const float*)d_in[2];
  const float* E       = (const float*)d_in[3];
  const float* Wv      = (const float*)d_in[4];
  const float* bv      = (const float*)d_in[5];
  const float* Wc      = (const float*)d_in[6];
  const float* bc      = (const float*)d_in[7];
  const float* Wt      = (const float*)d_in[8];
  const float* Wzt     = (const float*)d_in[9];
  float* out = (float*)d_out;

  char* w = (char*)d_ws;
  float* Lg     = (float*)(w);                   // 128*10016*4 = 5,128,192 B
  float* topP   = (float*)(w + 5128192);         // 512 f32 = 2048 B
  int*   topI   = (int*)  (w + 5130240);         // 512 int = 2048 B
  float* prob   = (float*)(w + 5132288);         // 128 f32 = 512 B
  int*   chainA = (int*)  (w + 5132800);         // 2048 int = 8192 B
  int*   chainB = (int*)  (w + 5140992);         // 2048 int = 8192 B

  k_init<<<1, 256, 0, stream>>>(loc_tar, chainA);

  int N = BB;
  int* cur = chainA;
  int* nxt = chainB;
  for (int i = 0; i < TT - 1; ++i) {
    int Mshift = (i == 0) ? 0 : ((i == 1) ? 2 : 3);
    dim3 g1(NTILE, (N + RPB - 1) / RPB);
    k_gemm<<<g1, 256, 0, stream>>>(E, zs, Wv, bv, cur, Lg, i, N, Mshift);
    k_red<<<N, 256, 0, stream>>>(Lg, topP, topI);
    k_beam<<<1, 64, 0, stream>>>(topP, topI, prob, cur, nxt, i);
    int* t2 = cur; cur = nxt; nxt = t2;
    N = (i == 0) ? BB * KK : BB * 2 * KK;
  }

  k_final<<<BB * (TT - 2), 64, 0, stream>>>(cur, E, Wc, bc, Wt, zt, Wzt, out);
}

// Round 10
// 2339.939 us; speedup vs baseline: 3.2273x; 1.7689x over previous
//
#include <hip/hip_runtime.h>
#include <math.h>

#define BB 16
#define TT 16
#define KK 4
#define VV 10003
#define DD 256
#define CC 64
#define NTILE 40        // ceil(V/256) v-tiles
#define RPB 16          // rows per k_gemm block
#define VP 10016        // padded row stride for logits scratch
#define MAXLEAF 192
#define MAXDEPTH 16
#define FNEG (-1e30f)

// ---------- top-4 list, f32 keys (tie-break: lower index wins) ----------
struct L4 { float v[4]; int ix[4]; };

__device__ __forceinline__ void l4_init(L4 &l) {
#pragma unroll
  for (int j = 0; j < 4; ++j) { l.v[j] = FNEG; l.ix[j] = 0x7fffffff; }
}
__device__ __forceinline__ bool better(float v, int ix, float v2, int ix2) {
  return (v > v2) || (v == v2 && ix < ix2);
}
__device__ __forceinline__ void l4_insert(L4 &l, float v, int ix) {
  if (!better(v, ix, l.v[3], l.ix[3])) return;
  int p = 3;
  while (p > 0 && better(v, ix, l.v[p-1], l.ix[p-1])) {
    l.v[p] = l.v[p-1]; l.ix[p] = l.ix[p-1]; --p;
  }
  l.v[p] = v; l.ix[p] = ix;
}
__device__ __forceinline__ void l4_merge(L4 &a, const L4 &b) {
  L4 r; int ia = 0, ib = 0;
#pragma unroll
  for (int j = 0; j < 4; ++j) {
    if (better(a.v[ia], a.ix[ia], b.v[ib], b.ix[ib])) {
      r.v[j] = a.v[ia]; r.ix[j] = a.ix[ia]; ++ia;
    } else {
      r.v[j] = b.v[ib]; r.ix[j] = b.ix[ib]; ++ib;
    }
  }
  a = r;
}

// ---------- numpy pairwise_sum replica ----------
// 8-accumulator block sum (numpy base case, 8 <= n <= 128) — bit-exact
__device__ float np_block_sum(const float* a, int n) {
  float r0=a[0],r1=a[1],r2=a[2],r3=a[3],r4=a[4],r5=a[5],r6=a[6],r7=a[7];
  int i;
  for (i = 8; i + 8 <= n; i += 8) {
    r0 += a[i+0]; r1 += a[i+1]; r2 += a[i+2]; r3 += a[i+3];
    r4 += a[i+4]; r5 += a[i+5]; r6 += a[i+6]; r7 += a[i+7];
  }
  float res = ((r0 + r1) + (r2 + r3)) + ((r4 + r5) + (r6 + r7));
  for (; i < n; ++i) res += a[i];
  return res;
}

// ---------- kernel 0: init chain ----------
__global__ void k_init(const int* __restrict__ loc_tar, int* __restrict__ chainA) {
  int t = threadIdx.x;            // 256 = B*T
  int b = t >> 4, j = t & 15;
  chainA[t] = (j == 0) ? loc_tar[b * TT] : 0;
}

// ---------- kernel 1: sgemm-mimic logits -> global scratch (UNCHANGED) --------
__global__ __launch_bounds__(256)
void k_gemm(const float* __restrict__ E, const float* __restrict__ zs,
            const float* __restrict__ Wv, const float* __restrict__ bv,
            const int* __restrict__ chain, float* __restrict__ Lg,
            int step, int N, int Mshift) {
  __shared__ float xs[RPB * DD];     // 16 KB
  __shared__ int cs[RPB];

  const int t = threadIdx.x;
  const int tile = blockIdx.x;
  const int n0 = blockIdx.y * RPB;
  const int v = tile * 256 + t;
  const int vok = (v < VV);
  const int vc = vok ? v : (VV - 1);

  if (t < RPB) {
    int n = n0 + t;
    int c = (n < N) ? chain[n * TT + step] : 0;
    if ((unsigned)c >= VV) c = 0;    // defensive
    cs[t] = c;
  }
  __syncthreads();

  // stage xs rows: h = E[c] + zs[b]  (single f32 add, np order)
  for (int e = t; e < RPB * DD; e += 256) {
    int r = e >> 8, d = e & 255;
    int n = n0 + r;
    int b = (n < N) ? (n >> Mshift) : 0;
    xs[e] = E[cs[r] * DD + d] + zs[b * DD + d];
  }
  __syncthreads();

  float acc[RPB];
#pragma unroll
  for (int r = 0; r < RPB; ++r) acc[r] = 0.f;

  // sequential-k fused-FMA chain per (row, col) — mimics BLAS sgemm micro-kernel
  for (int d = 0; d < DD; ++d) {
    float w = Wv[d * VV + vc];
#pragma unroll
    for (int r = 0; r < RPB; ++r) acc[r] = fmaf(xs[r * DD + d], w, acc[r]);
  }

  if (vok) {
    const float bvv = bv[v];
#pragma unroll
    for (int r = 0; r < RPB; ++r) {
      int n = n0 + r;
      if (n < N) Lg[(size_t)n * VP + v] = acc[r] + bvv;   // bias after gemm (np)
    }
  }
}

// ---------- kernel 2: per-row np-exact max/top4/pairwise-lse (UNCHANGED R9) ----
__global__ __launch_bounds__(256)
void k_red(const float* __restrict__ Lg, float* __restrict__ topP,
           int* __restrict__ topI) {
  __shared__ float row[VV];          // 40012 B (logits, then exp'd values)
  __shared__ float pm[256];          // 1 KB
  __shared__ float pv4[256 * 4];     // 4 KB
  __shared__ int   pi4[256 * 4];     // 4 KB
  __shared__ float leafsum[MAXLEAF]; // 768 B
  __shared__ int   lstart[MAXLEAF];
  __shared__ int   llen[MAXLEAF];
  __shared__ int   nleaf;
  __shared__ int   stkA[MAXDEPTH];   // iterative-traversal stacks (thread 0)
  __shared__ int   stkB[MAXDEPTH];
  __shared__ float stkV[MAXDEPTH];
  __shared__ char  stkS[MAXDEPTH];

  const int n = blockIdx.x;
  const int t = threadIdx.x;
  const float* grow = Lg + (size_t)n * VP;

  // coalesced load of the logit row into LDS
  for (int v = t; v < VV; v += 256) row[v] = grow[v];

  // thread 0: enumerate numpy-pairwise leaves (iterative DFS, left-first)
  if (t == 0) {
    int sp = 0, cnt = 0, base = 0, nc = VV;
    for (;;) {
      while (nc > 128) {
        int n2 = nc / 2; n2 -= n2 % 8;
        stkA[sp] = base + n2; stkB[sp] = nc - n2; ++sp;   // push right subtree
        nc = n2;                                          // descend left
      }
      lstart[cnt] = base; llen[cnt] = nc; ++cnt;          // leaf
      if (sp == 0) break;
      --sp; base = stkA[sp]; nc = stkB[sp];               // pop next right
    }
    nleaf = cnt;
  }
  __syncthreads();

  // per-thread exact max + top4 over v = t, t+256, ... (ascending)
  float m = FNEG;
  L4 top; l4_init(top);
  for (int v = t; v < VV; v += 256) {
    float x = row[v];
    if (x > m) m = x;
    l4_insert(top, x, v);
  }
  pm[t] = m;
#pragma unroll
  for (int j = 0; j < 4; ++j) { pv4[t * 4 + j] = top.v[j]; pi4[t * 4 + j] = top.ix[j]; }
  __syncthreads();

  // exact tree reduce (max + top4 set selection are order-independent)
  for (int str = 128; str >= 1; str >>= 1) {
    if (t < str) {
      if (pm[t + str] > pm[t]) pm[t] = pm[t + str];
      L4 a, b;
#pragma unroll
      for (int j = 0; j < 4; ++j) {
        a.v[j] = pv4[t * 4 + j];          a.ix[j] = pi4[t * 4 + j];
        b.v[j] = pv4[(t + str) * 4 + j];  b.ix[j] = pi4[(t + str) * 4 + j];
      }
      l4_merge(a, b);
#pragma unroll
      for (int j = 0; j < 4; ++j) { pv4[t * 4 + j] = a.v[j]; pi4[t * 4 + j] = a.ix[j]; }
    }
    __syncthreads();
  }
  const float gm = pm[0];

  // e = exp(x - m): f32 sub then f64-emulated f32 exp (same as R7/R8), in LDS
  for (int v = t; v < VV; v += 256)
    row[v] = (float)exp((double)(row[v] - gm));
  __syncthreads();

  // parallel leaf block-sums (numpy 8-accumulator base case, bit-exact)
  if (t < nleaf) leafsum[t] = np_block_sum(&row[lstart[t]], llen[t]);
  __syncthreads();

  // thread 0: iterative replay of recursion combines (identical association)
  if (t == 0) {
    int sp = 0, idx = 0, nc = VV;
    float resv;
    for (;;) {
      while (nc > 128) {
        int n2 = nc / 2; n2 -= n2 % 8;
        stkB[sp] = nc - n2; stkS[sp] = 0; ++sp;   // frame: right size, stage 0
        nc = n2;                                  // descend left
      }
      float val = leafsum[idx++];                 // leaf value
      while (sp > 0 && stkS[sp - 1] == 1) {       // unwind completed frames
        val = stkV[sp - 1] + val;                 // left + right (np order)
        --sp;
      }
      if (sp == 0) { resv = val; break; }
      stkV[sp - 1] = val; stkS[sp - 1] = 1;       // save left, descend right
      nc = stkB[sp - 1];
    }
    float ls = (float)log((double)resv);
#pragma unroll
    for (int j = 0; j < 4; ++j) {
      topP[n * 4 + j] = (pv4[j] - gm) - ls;   // (x - m) - log(s), two f32 subs
      topI[n * 4 + j] = pi4[j];
    }
  }
}

// ---------- kernel 3: beam update, wave-parallel (NO scratch arrays) ----------
// 512 threads = 16 batches x 32 candidates; identical decision arithmetic to
// the old selection sort: max value, lowest candidate index on exact f32 ties.
__global__ __launch_bounds__(512)
void k_beam(const float* __restrict__ topP, const int* __restrict__ topI,
            float* __restrict__ prob, const int* __restrict__ chain_cur,
            int* __restrict__ chain_next, int step) {
  __shared__ int sel_src[BB][8];
  __shared__ int sel_tok[BB][8];

  const int tid = threadIdx.x;
  const int b = tid >> 5;      // batch 0..15
  const int c = tid & 31;      // candidate 0..31

  if (step == 0) {
    // 64 dst chains (b,k): copy 16 ints each, set pos 1, store prob
    for (int e = tid; e < BB * KK * TT; e += 512) {
      int dst = e >> 4, q = e & 15;
      int bb = dst >> 2, kk = dst & 3;
      int val;
      if (q == 1) {
        int tok = topI[bb * 4 + kk]; if ((unsigned)tok >= VV) tok = 0;
        val = tok;
      } else {
        val = chain_cur[bb * TT + q];
      }
      chain_next[dst * TT + q] = val;
    }
    if (tid < BB * KK) {
      int bb = tid >> 2, kk = tid & 3;
      prob[bb * 8 + kk] = topP[bb * 4 + kk];
    }
    return;
  }

  const int M = (step == 1) ? 4 : 8;
  const int nc = M * 4;

  // lane's candidate value (same single f32 multiply as before)
  float act; 
  if (c < nc) {
    int m = c >> 2, k = c & 3;
    act = prob[b * 8 + m] * topP[(b * M + m) * 4 + k];
  } else {
    act = -INFINITY;
  }

  // 8 rounds of exact argmax over the 32-lane group (tie: lower c wins)
  for (int j = 0; j < 8; ++j) {
    float rv = act; int ri = c;
#pragma unroll
    for (int off = 1; off < 32; off <<= 1) {
      float v2 = __shfl_xor(rv, off, 32);
      int   i2 = __shfl_xor(ri, off, 32);
      if (v2 > rv || (v2 == rv && i2 < ri)) { rv = v2; ri = i2; }
    }
    if (c == ri) act = -INFINITY;          // mark used
    if (c == 0) {
      int m = ri >> 2, k = ri & 3;
      int src = b * M + m;
      int tok = topI[src * 4 + k]; if ((unsigned)tok >= VV) tok = 0;
      sel_src[b][j] = src;
      sel_tok[b][j] = tok;
      prob[b * 8 + j] = rv;                // same value the old code stored
    }
  }
  __syncthreads();

  // parallel chain copy: 16 batches x 8 beams x 16 ints = 2048
  for (int e = tid; e < BB * 8 * TT; e += 512) {
    int dst = e >> 4, q = e & 15;
    int bb = dst >> 3, j = dst & 7;
    int src = sel_src[bb][j];
    int val = (q == step + 1) ? sel_tok[bb][j] : chain_cur[src * TT + q];
    chain_next[dst * TT + q] = val;
  }
}

// ---------- kernel 4: finalize: loc_chain + tim_chain (UNCHANGED) ----------
__global__ __launch_bounds__(64)
void k_final(const int* __restrict__ chain, const float* __restrict__ E,
             const float* __restrict__ Wc, const float* __restrict__ bc,
             const float* __restrict__ Wt, const float* __restrict__ zt,
             const float* __restrict__ Wzt, float* __restrict__ out) {
  int blk = blockIdx.x;           // 224 = B*(T-2)
  int b = blk / (TT - 2), t = blk % (TT - 2);
  int lane = threadIdx.x;         // 64 = C
  int loc = chain[(b * 8) * TT + 1 + t];   // best beam, positions 1..T-2
  if ((unsigned)loc >= VV) loc = 0;        // defensive
  double acc = (double)bc[lane];
  const float* er = E + loc * DD;
  for (int d = 0; d < DD; ++d) acc += (double)er[d] * (double)Wc[d * CC + lane];
  double val = tanh(acc) * (double)Wt[lane];
  const float* ztr = zt + b * DD;
#pragma unroll
  for (int q = 0; q < 4; ++q) val += (double)ztr[lane * 4 + q] * (double)Wzt[lane * 4 + q];
  for (int off = 32; off; off >>= 1) val += __shfl_down(val, off);
  if (lane == 0) {
    out[b * (TT - 2) + t] = (float)loc;                 // loc_chain as float
    out[BB * (TT - 2) + b * (TT - 2) + t] = (float)val; // tim_chain
  }
}

// ---------- host ----------
extern "C" void kernel_launch(void* const* d_in, const int* in_sizes, int n_in,
                              void* d_out, int out_size, void* d_ws, size_t ws_size,
                              hipStream_t stream) {
  const int*   loc_tar = (const int*)  d_in[0];
  const float* zs      = (const float*)d_in[1];
  const float* zt      = (const float*)d_in[2];
  const float* E       = (const float*)d_in[3];
  const float* Wv      = (const float*)d_in[4];
  const float* bv      = (const float*)d_in[5];
  const float* Wc      = (const float*)d_in[6];
  const float* bc      = (const float*)d_in[7];
  const float* Wt      = (const float*)d_in[8];
  const float* Wzt     = (const float*)d_in[9];
  float* out = (float*)d_out;

  char* w = (char*)d_ws;
  float* Lg     = (float*)(w);                   // 128*10016*4 = 5,128,192 B
  float* topP   = (float*)(w + 5128192);         // 512 f32 = 2048 B
  int*   topI   = (int*)  (w + 5130240);         // 512 int = 2048 B
  float* prob   = (float*)(w + 5132288);         // 128 f32 = 512 B
  int*   chainA = (int*)  (w + 5132800);         // 2048 int = 8192 B
  int*   chainB = (int*)  (w + 5140992);         // 2048 int = 8192 B

  k_init<<<1, 256, 0, stream>>>(loc_tar, chainA);

  int N = BB;
  int* cur = chainA;
  int* nxt = chainB;
  for (int i = 0; i < TT - 1; ++i) {
    int Mshift = (i == 0) ? 0 : ((i == 1) ? 2 : 3);
    dim3 g1(NTILE, (N + RPB - 1) / RPB);
    k_gemm<<<g1, 256, 0, stream>>>(E, zs, Wv, bv, cur, Lg, i, N, Mshift);
    k_red<<<N, 256, 0, stream>>>(Lg, topP, topI);
    k_beam<<<1, 512, 0, stream>>>(topP, topI, prob, cur, nxt, i);
    int* t2 = cur; cur = nxt; nxt = t2;
    N = (i == 0) ? BB * KK : BB * 2 * KK;
  }

  k_final<<<BB * (TT - 2), 64, 0, stream>>>(cur, E, Wc, bc, Wt, zt, Wzt, out);
}

// Round 11
// 2113.928 us; speedup vs baseline: 3.5724x; 1.1069x over previous
//
#include <hip/hip_runtime.h>
#include <math.h>

#define BB 16
#define TT 16
#define KK 4
#define VV 10003
#define DD 256
#define CC 64
#define NTILE 40        // ceil(V/256) v-tiles
#define RPB 16          // rows per k_gemm block
#define VP 10016        // padded row stride for logits scratch
#define MAXLEAF 192
#define MAXDEPTH 16
#define FNEG (-1e30f)

// ---------- top-4 list, f32 keys (tie-break: lower index wins) ----------
struct L4 { float v[4]; int ix[4]; };

__device__ __forceinline__ void l4_init(L4 &l) {
#pragma unroll
  for (int j = 0; j < 4; ++j) { l.v[j] = FNEG; l.ix[j] = 0x7fffffff; }
}
__device__ __forceinline__ bool better(float v, int ix, float v2, int ix2) {
  return (v > v2) || (v == v2 && ix < ix2);
}
__device__ __forceinline__ void l4_insert(L4 &l, float v, int ix) {
  if (!better(v, ix, l.v[3], l.ix[3])) return;
  int p = 3;
  while (p > 0 && better(v, ix, l.v[p-1], l.ix[p-1])) {
    l.v[p] = l.v[p-1]; l.ix[p] = l.ix[p-1]; --p;
  }
  l.v[p] = v; l.ix[p] = ix;
}
__device__ __forceinline__ void l4_merge(L4 &a, const L4 &b) {
  L4 r; int ia = 0, ib = 0;
#pragma unroll
  for (int j = 0; j < 4; ++j) {
    if (better(a.v[ia], a.ix[ia], b.v[ib], b.ix[ib])) {
      r.v[j] = a.v[ia]; r.ix[j] = a.ix[ia]; ++ia;
    } else {
      r.v[j] = b.v[ib]; r.ix[j] = b.ix[ib]; ++ib;
    }
  }
  a = r;
}

// ---------- numpy pairwise_sum replica ----------
// 8-accumulator block sum (numpy base case, 8 <= n <= 128) — bit-exact
__device__ float np_block_sum(const float* a, int n) {
  float r0=a[0],r1=a[1],r2=a[2],r3=a[3],r4=a[4],r5=a[5],r6=a[6],r7=a[7];
  int i;
  for (i = 8; i + 8 <= n; i += 8) {
    r0 += a[i+0]; r1 += a[i+1]; r2 += a[i+2]; r3 += a[i+3];
    r4 += a[i+4]; r5 += a[i+5]; r6 += a[i+6]; r7 += a[i+7];
  }
  float res = ((r0 + r1) + (r2 + r3)) + ((r4 + r5) + (r6 + r7));
  for (; i < n; ++i) res += a[i];
  return res;
}

// ---------- kernel 0: init chain ----------
__global__ void k_init(const int* __restrict__ loc_tar, int* __restrict__ chainA) {
  int t = threadIdx.x;            // 256 = B*T
  int b = t >> 4, j = t & 15;
  chainA[t] = (j == 0) ? loc_tar[b * TT] : 0;
}

// ---------- kernel 1: sgemm-mimic logits, LDS-staged Wv chunks ---------------
// Same arithmetic as R10 (single f32 accumulator per (row,col), fmaf chain in
// strictly ascending d) — only the data path for Wv changed (global->LDS).
__global__ __launch_bounds__(256)
void k_gemm(const float* __restrict__ E, const float* __restrict__ zs,
            const float* __restrict__ Wv, const float* __restrict__ bv,
            const int* __restrict__ chain, float* __restrict__ Lg,
            int step, int N, int Mshift) {
  __shared__ float xs[RPB * DD];     // 16 KB  (h rows)
  __shared__ float wsh[32 * 256];    // 32 KB  (Wv chunk: 32 d-rows x 256 cols)
  __shared__ int cs[RPB];

  const int t = threadIdx.x;
  const int tile = blockIdx.x;
  const int n0 = blockIdx.y * RPB;
  const int v0 = tile * 256;
  const int v = v0 + t;
  const int vok = (v < VV);

  if (t < RPB) {
    int n = n0 + t;
    int c = (n < N) ? chain[n * TT + step] : 0;
    if ((unsigned)c >= VV) c = 0;    // defensive
    cs[t] = c;
  }
  __syncthreads();

  // stage xs rows: h = E[c] + zs[b]  (single f32 add, np order)
  for (int e = t; e < RPB * DD; e += 256) {
    int r = e >> 8, d = e & 255;
    int n = n0 + r;
    int b = (n < N) ? (n >> Mshift) : 0;
    xs[e] = E[cs[r] * DD + d] + zs[b * DD + d];
  }

  float acc[RPB];
#pragma unroll
  for (int r = 0; r < RPB; ++r) acc[r] = 0.f;

  for (int dt = 0; dt < 8; ++dt) {
    __syncthreads();   // xs ready (first iter) / wsh consumed (later iters)
    // stage Wv chunk: thread loads col t for dd=0..31 (independent, coalesced)
    for (int e = t; e < 32 * 256; e += 256) {
      int dd = e >> 8, cc = e & 255;
      int vg = v0 + cc;
      wsh[e] = Wv[(size_t)(dt * 32 + dd) * VV + (vg < VV ? vg : VV - 1)];
    }
    __syncthreads();
    // sequential-k fused-FMA chains (d ascending) from LDS
#pragma unroll 4
    for (int dd = 0; dd < 32; ++dd) {
      const float w = wsh[dd * 256 + t];
      const int d = dt * 32 + dd;
#pragma unroll
      for (int r = 0; r < RPB; ++r) acc[r] = fmaf(xs[r * DD + d], w, acc[r]);
    }
  }

  if (vok) {
    const float bvv = bv[v];
#pragma unroll
    for (int r = 0; r < RPB; ++r) {
      int n = n0 + r;
      if (n < N) Lg[(size_t)n * VP + v] = acc[r] + bvv;   // bias after gemm (np)
    }
  }
}

// ---------- kernel 2: per-row np-exact max/top4/pairwise-lse (UNCHANGED R9) ----
__global__ __launch_bounds__(256)
void k_red(const float* __restrict__ Lg, float* __restrict__ topP,
           int* __restrict__ topI) {
  __shared__ float row[VV];          // 40012 B (logits, then exp'd values)
  __shared__ float pm[256];          // 1 KB
  __shared__ float pv4[256 * 4];     // 4 KB
  __shared__ int   pi4[256 * 4];     // 4 KB
  __shared__ float leafsum[MAXLEAF]; // 768 B
  __shared__ int   lstart[MAXLEAF];
  __shared__ int   llen[MAXLEAF];
  __shared__ int   nleaf;
  __shared__ int   stkA[MAXDEPTH];   // iterative-traversal stacks (thread 0)
  __shared__ int   stkB[MAXDEPTH];
  __shared__ float stkV[MAXDEPTH];
  __shared__ char  stkS[MAXDEPTH];

  const int n = blockIdx.x;
  const int t = threadIdx.x;
  const float* grow = Lg + (size_t)n * VP;

  // coalesced load of the logit row into LDS
  for (int v = t; v < VV; v += 256) row[v] = grow[v];

  // thread 0: enumerate numpy-pairwise leaves (iterative DFS, left-first)
  if (t == 0) {
    int sp = 0, cnt = 0, base = 0, nc = VV;
    for (;;) {
      while (nc > 128) {
        int n2 = nc / 2; n2 -= n2 % 8;
        stkA[sp] = base + n2; stkB[sp] = nc - n2; ++sp;   // push right subtree
        nc = n2;                                          // descend left
      }
      lstart[cnt] = base; llen[cnt] = nc; ++cnt;          // leaf
      if (sp == 0) break;
      --sp; base = stkA[sp]; nc = stkB[sp];               // pop next right
    }
    nleaf = cnt;
  }
  __syncthreads();

  // per-thread exact max + top4 over v = t, t+256, ... (ascending)
  float m = FNEG;
  L4 top; l4_init(top);
  for (int v = t; v < VV; v += 256) {
    float x = row[v];
    if (x > m) m = x;
    l4_insert(top, x, v);
  }
  pm[t] = m;
#pragma unroll
  for (int j = 0; j < 4; ++j) { pv4[t * 4 + j] = top.v[j]; pi4[t * 4 + j] = top.ix[j]; }
  __syncthreads();

  // exact tree reduce (max + top4 set selection are order-independent)
  for (int str = 128; str >= 1; str >>= 1) {
    if (t < str) {
      if (pm[t + str] > pm[t]) pm[t] = pm[t + str];
      L4 a, b;
#pragma unroll
      for (int j = 0; j < 4; ++j) {
        a.v[j] = pv4[t * 4 + j];          a.ix[j] = pi4[t * 4 + j];
        b.v[j] = pv4[(t + str) * 4 + j];  b.ix[j] = pi4[(t + str) * 4 + j];
      }
      l4_merge(a, b);
#pragma unroll
      for (int j = 0; j < 4; ++j) { pv4[t * 4 + j] = a.v[j]; pi4[t * 4 + j] = a.ix[j]; }
    }
    __syncthreads();
  }
  const float gm = pm[0];

  // e = exp(x - m): f32 sub then f64-emulated f32 exp (same as R7/R8), in LDS
  for (int v = t; v < VV; v += 256)
    row[v] = (float)exp((double)(row[v] - gm));
  __syncthreads();

  // parallel leaf block-sums (numpy 8-accumulator base case, bit-exact)
  if (t < nleaf) leafsum[t] = np_block_sum(&row[lstart[t]], llen[t]);
  __syncthreads();

  // thread 0: iterative replay of recursion combines (identical association)
  if (t == 0) {
    int sp = 0, idx = 0, nc = VV;
    float resv;
    for (;;) {
      while (nc > 128) {
        int n2 = nc / 2; n2 -= n2 % 8;
        stkB[sp] = nc - n2; stkS[sp] = 0; ++sp;   // frame: right size, stage 0
        nc = n2;                                  // descend left
      }
      float val = leafsum[idx++];                 // leaf value
      while (sp > 0 && stkS[sp - 1] == 1) {       // unwind completed frames
        val = stkV[sp - 1] + val;                 // left + right (np order)
        --sp;
      }
      if (sp == 0) { resv = val; break; }
      stkV[sp - 1] = val; stkS[sp - 1] = 1;       // save left, descend right
      nc = stkB[sp - 1];
    }
    float ls = (float)log((double)resv);
#pragma unroll
    for (int j = 0; j < 4; ++j) {
      topP[n * 4 + j] = (pv4[j] - gm) - ls;   // (x - m) - log(s), two f32 subs
      topI[n * 4 + j] = pi4[j];
    }
  }
}

// ---------- kernel 3: beam update, wave-parallel (UNCHANGED R10) ----------
__global__ __launch_bounds__(512)
void k_beam(const float* __restrict__ topP, const int* __restrict__ topI,
            float* __restrict__ prob, const int* __restrict__ chain_cur,
            int* __restrict__ chain_next, int step) {
  __shared__ int sel_src[BB][8];
  __shared__ int sel_tok[BB][8];

  const int tid = threadIdx.x;
  const int b = tid >> 5;      // batch 0..15
  const int c = tid & 31;      // candidate 0..31

  if (step == 0) {
    for (int e = tid; e < BB * KK * TT; e += 512) {
      int dst = e >> 4, q = e & 15;
      int bb = dst >> 2, kk = dst & 3;
      int val;
      if (q == 1) {
        int tok = topI[bb * 4 + kk]; if ((unsigned)tok >= VV) tok = 0;
        val = tok;
      } else {
        val = chain_cur[bb * TT + q];
      }
      chain_next[dst * TT + q] = val;
    }
    if (tid < BB * KK) {
      int bb = tid >> 2, kk = tid & 3;
      prob[bb * 8 + kk] = topP[bb * 4 + kk];
    }
    return;
  }

  const int M = (step == 1) ? 4 : 8;
  const int nc = M * 4;

  float act;
  if (c < nc) {
    int m = c >> 2, k = c & 3;
    act = prob[b * 8 + m] * topP[(b * M + m) * 4 + k];
  } else {
    act = -INFINITY;
  }

  for (int j = 0; j < 8; ++j) {
    float rv = act; int ri = c;
#pragma unroll
    for (int off = 1; off < 32; off <<= 1) {
      float v2 = __shfl_xor(rv, off, 32);
      int   i2 = __shfl_xor(ri, off, 32);
      if (v2 > rv || (v2 == rv && i2 < ri)) { rv = v2; ri = i2; }
    }
    if (c == ri) act = -INFINITY;          // mark used
    if (c == 0) {
      int m = ri >> 2, k = ri & 3;
      int src = b * M + m;
      int tok = topI[src * 4 + k]; if ((unsigned)tok >= VV) tok = 0;
      sel_src[b][j] = src;
      sel_tok[b][j] = tok;
      prob[b * 8 + j] = rv;
    }
  }
  __syncthreads();

  for (int e = tid; e < BB * 8 * TT; e += 512) {
    int dst = e >> 4, q = e & 15;
    int bb = dst >> 3, j = dst & 7;
    int src = sel_src[bb][j];
    int val = (q == step + 1) ? sel_tok[bb][j] : chain_cur[src * TT + q];
    chain_next[dst * TT + q] = val;
  }
}

// ---------- kernel 4: finalize: loc_chain + tim_chain (UNCHANGED) ----------
__global__ __launch_bounds__(64)
void k_final(const int* __restrict__ chain, const float* __restrict__ E,
             const float* __restrict__ Wc, const float* __restrict__ bc,
             const float* __restrict__ Wt, const float* __restrict__ zt,
             const float* __restrict__ Wzt, float* __restrict__ out) {
  int blk = blockIdx.x;           // 224 = B*(T-2)
  int b = blk / (TT - 2), t = blk % (TT - 2);
  int lane = threadIdx.x;         // 64 = C
  int loc = chain[(b * 8) * TT + 1 + t];   // best beam, positions 1..T-2
  if ((unsigned)loc >= VV) loc = 0;        // defensive
  double acc = (double)bc[lane];
  const float* er = E + loc * DD;
  for (int d = 0; d < DD; ++d) acc += (double)er[d] * (double)Wc[d * CC + lane];
  double val = tanh(acc) * (double)Wt[lane];
  const float* ztr = zt + b * DD;
#pragma unroll
  for (int q = 0; q < 4; ++q) val += (double)ztr[lane * 4 + q] * (double)Wzt[lane * 4 + q];
  for (int off = 32; off; off >>= 1) val += __shfl_down(val, off);
  if (lane == 0) {
    out[b * (TT - 2) + t] = (float)loc;                 // loc_chain as float
    out[BB * (TT - 2) + b * (TT - 2) + t] = (float)val; // tim_chain
  }
}

// ---------- host ----------
extern "C" void kernel_launch(void* const* d_in, const int* in_sizes, int n_in,
                              void* d_out, int out_size, void* d_ws, size_t ws_size,
                              hipStream_t stream) {
  const int*   loc_tar = (const int*)  d_in[0];
  const float* zs      = (const float*)d_in[1];
  const float* zt      = (const float*)d_in[2];
  const float* E       = (const float*)d_in[3];
  const float* Wv      = (const float*)d_in[4];
  const float* bv      = (const float*)d_in[5];
  const float* Wc      = (const float*)d_in[6];
  const float* bc      = (const float*)d_in[7];
  const float* Wt      = (const float*)d_in[8];
  const float* Wzt     = (const float*)d_in[9];
  float* out = (float*)d_out;

  char* w = (char*)d_ws;
  float* Lg     = (float*)(w);                   // 128*10016*4 = 5,128,192 B
  float* topP   = (float*)(w + 5128192);         // 512 f32 = 2048 B
  int*   topI   = (int*)  (w + 5130240);         // 512 int = 2048 B
  float* prob   = (float*)(w + 5132288);         // 128 f32 = 512 B
  int*   chainA = (int*)  (w + 5132800);         // 2048 int = 8192 B
  int*   chainB = (int*)  (w + 5140992);         // 2048 int = 8192 B

  k_init<<<1, 256, 0, stream>>>(loc_tar, chainA);

  int N = BB;
  int* cur = chainA;
  int* nxt = chainB;
  for (int i = 0; i < TT - 1; ++i) {
    int Mshift = (i == 0) ? 0 : ((i == 1) ? 2 : 3);
    dim3 g1(NTILE, (N + RPB - 1) / RPB);
    k_gemm<<<g1, 256, 0, stream>>>(E, zs, Wv, bv, cur, Lg, i, N, Mshift);
    k_red<<<N, 256, 0, stream>>>(Lg, topP, topI);
    k_beam<<<1, 512, 0, stream>>>(topP, topI, prob, cur, nxt, i);
    int* t2 = cur; cur = nxt; nxt = t2;
    N = (i == 0) ? BB * KK : BB * 2 * KK;
  }

  k_final<<<BB * (TT - 2), 64, 0, stream>>>(cur, E, Wc, bc, Wt, zt, Wzt, out);
}

// Round 12
// 1370.454 us; speedup vs baseline: 5.5104x; 1.5425x over previous
//
#include <hip/hip_runtime.h>
#include <math.h>

#define BB 16
#define TT 16
#define KK 4
#define VV 10003
#define DD 256
#define CC 64
#define NTILE 40        // ceil(V/256) v-tiles
#define RPB 16          // rows per k_gemm block
#define VP 10016        // padded row stride for logits scratch
#define FNEG (-1e30f)

// ---------- top-4 list, f32 keys (tie-break: lower index wins) ----------
struct L4 { float v[4]; int ix[4]; };

__device__ __forceinline__ void l4_init(L4 &l) {
#pragma unroll
  for (int j = 0; j < 4; ++j) { l.v[j] = FNEG; l.ix[j] = 0x7fffffff; }
}
__device__ __forceinline__ bool better(float v, int ix, float v2, int ix2) {
  return (v > v2) || (v == v2 && ix < ix2);
}
__device__ __forceinline__ void l4_insert(L4 &l, float v, int ix) {
  if (!better(v, ix, l.v[3], l.ix[3])) return;
  int p = 3;
  while (p > 0 && better(v, ix, l.v[p-1], l.ix[p-1])) {
    l.v[p] = l.v[p-1]; l.ix[p] = l.ix[p-1]; --p;
  }
  l.v[p] = v; l.ix[p] = ix;
}
__device__ __forceinline__ void l4_merge(L4 &a, const L4 &b) {
  L4 r; int ia = 0, ib = 0;
#pragma unroll
  for (int j = 0; j < 4; ++j) {
    if (better(a.v[ia], a.ix[ia], b.v[ib], b.ix[ib])) {
      r.v[j] = a.v[ia]; r.ix[j] = a.ix[ia]; ++ia;
    } else {
      r.v[j] = b.v[ib]; r.ix[j] = b.ix[ib]; ++ib;
    }
  }
  a = r;
}

// ---------- numpy pairwise_sum base case (8 <= n <= 128) — bit-exact ----------
__device__ float np_block_sum(const float* a, int n) {
  float r0=a[0],r1=a[1],r2=a[2],r3=a[3],r4=a[4],r5=a[5],r6=a[6],r7=a[7];
  int i;
  for (i = 8; i + 8 <= n; i += 8) {
    r0 += a[i+0]; r1 += a[i+1]; r2 += a[i+2]; r3 += a[i+3];
    r4 += a[i+4]; r5 += a[i+5]; r6 += a[i+6]; r7 += a[i+7];
  }
  float res = ((r0 + r1) + (r2 + r3)) + ((r4 + r5) + (r6 + r7));
  for (; i < n; ++i) res += a[i];
  return res;
}

// ---------- kernel 0: init chain ----------
__global__ void k_init(const int* __restrict__ loc_tar, int* __restrict__ chainA) {
  int t = threadIdx.x;            // 256 = B*T
  int b = t >> 4, j = t & 15;
  chainA[t] = (j == 0) ? loc_tar[b * TT] : 0;
}

// ---------- kernel 1: sgemm-mimic logits, LDS-staged Wv chunks (UNCHANGED) ----
__global__ __launch_bounds__(256)
void k_gemm(const float* __restrict__ E, const float* __restrict__ zs,
            const float* __restrict__ Wv, const float* __restrict__ bv,
            const int* __restrict__ chain, float* __restrict__ Lg,
            int step, int N, int Mshift) {
  __shared__ float xs[RPB * DD];     // 16 KB  (h rows)
  __shared__ float wsh[32 * 256];    // 32 KB  (Wv chunk: 32 d-rows x 256 cols)
  __shared__ int cs[RPB];

  const int t = threadIdx.x;
  const int tile = blockIdx.x;
  const int n0 = blockIdx.y * RPB;
  const int v0 = tile * 256;
  const int v = v0 + t;
  const int vok = (v < VV);

  if (t < RPB) {
    int n = n0 + t;
    int c = (n < N) ? chain[n * TT + step] : 0;
    if ((unsigned)c >= VV) c = 0;    // defensive
    cs[t] = c;
  }
  __syncthreads();

  // stage xs rows: h = E[c] + zs[b]  (single f32 add, np order)
  for (int e = t; e < RPB * DD; e += 256) {
    int r = e >> 8, d = e & 255;
    int n = n0 + r;
    int b = (n < N) ? (n >> Mshift) : 0;
    xs[e] = E[cs[r] * DD + d] + zs[b * DD + d];
  }

  float acc[RPB];
#pragma unroll
  for (int r = 0; r < RPB; ++r) acc[r] = 0.f;

  for (int dt = 0; dt < 8; ++dt) {
    __syncthreads();   // xs ready (first iter) / wsh consumed (later iters)
    for (int e = t; e < 32 * 256; e += 256) {
      int dd = e >> 8, cc = e & 255;
      int vg = v0 + cc;
      wsh[e] = Wv[(size_t)(dt * 32 + dd) * VV + (vg < VV ? vg : VV - 1)];
    }
    __syncthreads();
#pragma unroll 4
    for (int dd = 0; dd < 32; ++dd) {
      const float w = wsh[dd * 256 + t];
      const int d = dt * 32 + dd;
#pragma unroll
      for (int r = 0; r < RPB; ++r) acc[r] = fmaf(xs[r * DD + d], w, acc[r]);
    }
  }

  if (vok) {
    const float bvv = bv[v];
#pragma unroll
    for (int r = 0; r < RPB; ++r) {
      int n = n0 + r;
      if (n < N) Lg[(size_t)n * VP + v] = acc[r] + bvv;   // bias after gemm (np)
    }
  }
}

// ---------- kernel 2: np-exact max/top4/pairwise-lse, fully parallel ----------
// For VV=10003 the numpy pairwise recursion is a PERFECT depth-7 binary tree
// (level-k sizes in [10003/2^k-15, 10003/2^k+15]: level-6 sizes in [141,171]
// all split; level-7 sizes in [63,93] all leaves). Heap-indexed nodes 0..254;
// build top-down in 7 parallel steps, evaluate bottom-up in 7 parallel
// combines — identical association to the serial DFS replay.
__global__ __launch_bounds__(256)
void k_red(const float* __restrict__ Lg, float* __restrict__ topP,
           int* __restrict__ topI) {
  __shared__ float row[VV];          // 40012 B (logits, then exp'd values)
  __shared__ float pm[256];
  __shared__ float pv4[256 * 4];
  __shared__ int   pi4[256 * 4];
  __shared__ int   segBase[255];     // heap: node -> segment start
  __shared__ int   segN[255];        // heap: node -> segment size
  __shared__ float val[255];         // heap: node -> pairwise sum

  const int n = blockIdx.x;
  const int t = threadIdx.x;
  const float* grow = Lg + (size_t)n * VP;

  // coalesced load of the logit row into LDS
  for (int v = t; v < VV; v += 256) row[v] = grow[v];

  // build segment tree top-down (7 parallel levels, numpy split rule)
  if (t == 0) { segBase[0] = 0; segN[0] = VV; }
  __syncthreads();
  for (int L = 0; L < 7; ++L) {
    int first = (1 << L) - 1, cnt = 1 << L;
    if (t < cnt) {
      int p = first + t;
      int np_ = segN[p], bp = segBase[p];
      int n2 = np_ / 2; n2 -= n2 % 8;
      segBase[2 * p + 1] = bp;       segN[2 * p + 1] = n2;
      segBase[2 * p + 2] = bp + n2;  segN[2 * p + 2] = np_ - n2;
    }
    __syncthreads();
  }

  // per-thread exact max + top4 over v = t, t+256, ... (ascending)
  float m = FNEG;
  L4 top; l4_init(top);
  for (int v = t; v < VV; v += 256) {
    float x = row[v];
    if (x > m) m = x;
    l4_insert(top, x, v);
  }
  pm[t] = m;
#pragma unroll
  for (int j = 0; j < 4; ++j) { pv4[t * 4 + j] = top.v[j]; pi4[t * 4 + j] = top.ix[j]; }
  __syncthreads();

  // exact tree reduce (max + top4 set selection are order-independent)
  for (int str = 128; str >= 1; str >>= 1) {
    if (t < str) {
      if (pm[t + str] > pm[t]) pm[t] = pm[t + str];
      L4 a, b;
#pragma unroll
      for (int j = 0; j < 4; ++j) {
        a.v[j] = pv4[t * 4 + j];          a.ix[j] = pi4[t * 4 + j];
        b.v[j] = pv4[(t + str) * 4 + j];  b.ix[j] = pi4[(t + str) * 4 + j];
      }
      l4_merge(a, b);
#pragma unroll
      for (int j = 0; j < 4; ++j) { pv4[t * 4 + j] = a.v[j]; pi4[t * 4 + j] = a.ix[j]; }
    }
    __syncthreads();
  }
  const float gm = pm[0];

  // e = exp(x - m): f32 sub then f64-emulated f32 exp (same as R7-R11), in LDS
  for (int v = t; v < VV; v += 256)
    row[v] = (float)exp((double)(row[v] - gm));
  __syncthreads();

  // 128 parallel leaf block-sums (numpy 8-accumulator base case, bit-exact)
  if (t < 128) {
    int nd = 127 + t;
    val[nd] = np_block_sum(&row[segBase[nd]], segN[nd]);
  }
  __syncthreads();

  // bottom-up combines: val[p] = val[left] + val[right]  (numpy association)
  for (int L = 6; L >= 0; --L) {
    int first = (1 << L) - 1, cnt = 1 << L;
    if (t < cnt) {
      int p = first + t;
      val[p] = val[2 * p + 1] + val[2 * p + 2];
    }
    __syncthreads();
  }

  if (t == 0) {
    float ls = (float)log((double)val[0]);
#pragma unroll
    for (int j = 0; j < 4; ++j) {
      topP[n * 4 + j] = (pv4[j] - gm) - ls;   // (x - m) - log(s), two f32 subs
      topI[n * 4 + j] = pi4[j];
    }
  }
}

// ---------- kernel 3: beam update, wave-parallel (UNCHANGED R10) ----------
__global__ __launch_bounds__(512)
void k_beam(const float* __restrict__ topP, const int* __restrict__ topI,
            float* __restrict__ prob, const int* __restrict__ chain_cur,
            int* __restrict__ chain_next, int step) {
  __shared__ int sel_src[BB][8];
  __shared__ int sel_tok[BB][8];

  const int tid = threadIdx.x;
  const int b = tid >> 5;      // batch 0..15
  const int c = tid & 31;      // candidate 0..31

  if (step == 0) {
    for (int e = tid; e < BB * KK * TT; e += 512) {
      int dst = e >> 4, q = e & 15;
      int bb = dst >> 2, kk = dst & 3;
      int val;
      if (q == 1) {
        int tok = topI[bb * 4 + kk]; if ((unsigned)tok >= VV) tok = 0;
        val = tok;
      } else {
        val = chain_cur[bb * TT + q];
      }
      chain_next[dst * TT + q] = val;
    }
    if (tid < BB * KK) {
      int bb = tid >> 2, kk = tid & 3;
      prob[bb * 8 + kk] = topP[bb * 4 + kk];
    }
    return;
  }

  const int M = (step == 1) ? 4 : 8;
  const int nc = M * 4;

  float act;
  if (c < nc) {
    int m = c >> 2, k = c & 3;
    act = prob[b * 8 + m] * topP[(b * M + m) * 4 + k];
  } else {
    act = -INFINITY;
  }

  for (int j = 0; j < 8; ++j) {
    float rv = act; int ri = c;
#pragma unroll
    for (int off = 1; off < 32; off <<= 1) {
      float v2 = __shfl_xor(rv, off, 32);
      int   i2 = __shfl_xor(ri, off, 32);
      if (v2 > rv || (v2 == rv && i2 < ri)) { rv = v2; ri = i2; }
    }
    if (c == ri) act = -INFINITY;          // mark used
    if (c == 0) {
      int m = ri >> 2, k = ri & 3;
      int src = b * M + m;
      int tok = topI[src * 4 + k]; if ((unsigned)tok >= VV) tok = 0;
      sel_src[b][j] = src;
      sel_tok[b][j] = tok;
      prob[b * 8 + j] = rv;
    }
  }
  __syncthreads();

  for (int e = tid; e < BB * 8 * TT; e += 512) {
    int dst = e >> 4, q = e & 15;
    int bb = dst >> 3, j = dst & 7;
    int src = sel_src[bb][j];
    int val = (q == step + 1) ? sel_tok[bb][j] : chain_cur[src * TT + q];
    chain_next[dst * TT + q] = val;
  }
}

// ---------- kernel 4: finalize: loc_chain + tim_chain (UNCHANGED) ----------
__global__ __launch_bounds__(64)
void k_final(const int* __restrict__ chain, const float* __restrict__ E,
             const float* __restrict__ Wc, const float* __restrict__ bc,
             const float* __restrict__ Wt, const float* __restrict__ zt,
             const float* __restrict__ Wzt, float* __restrict__ out) {
  int blk = blockIdx.x;           // 224 = B*(T-2)
  int b = blk / (TT - 2), t = blk % (TT - 2);
  int lane = threadIdx.x;         // 64 = C
  int loc = chain[(b * 8) * TT + 1 + t];   // best beam, positions 1..T-2
  if ((unsigned)loc >= VV) loc = 0;        // defensive
  double acc = (double)bc[lane];
  const float* er = E + loc * DD;
  for (int d = 0; d < DD; ++d) acc += (double)er[d] * (double)Wc[d * CC + lane];
  double val = tanh(acc) * (double)Wt[lane];
  const float* ztr = zt + b * DD;
#pragma unroll
  for (int q = 0; q < 4; ++q) val += (double)ztr[lane * 4 + q] * (double)Wzt[lane * 4 + q];
  for (int off = 32; off; off >>= 1) val += __shfl_down(val, off);
  if (lane == 0) {
    out[b * (TT - 2) + t] = (float)loc;                 // loc_chain as float
    out[BB * (TT - 2) + b * (TT - 2) + t] = (float)val; // tim_chain
  }
}

// ---------- host ----------
extern "C" void kernel_launch(void* const* d_in, const int* in_sizes, int n_in,
                              void* d_out, int out_size, void* d_ws, size_t ws_size,
                              hipStream_t stream) {
  const int*   loc_tar = (const int*)  d_in[0];
  const float* zs      = (const float*)d_in[1];
  const float* zt      = (const float*)d_in[2];
  const float* E       = (const float*)d_in[3];
  const float* Wv      = (const float*)d_in[4];
  const float* bv      = (const float*)d_in[5];
  const float* Wc      = (const float*)d_in[6];
  const float* bc      = (const float*)d_in[7];
  const float* Wt      = (const float*)d_in[8];
  const float* Wzt     = (const float*)d_in[9];
  float* out = (float*)d_out;

  char* w = (char*)d_ws;
  float* Lg     = (float*)(w);                   // 128*10016*4 = 5,128,192 B
  float* topP   = (float*)(w + 5128192);         // 512 f32 = 2048 B
  int*   topI   = (int*)  (w + 5130240);         // 512 int = 2048 B
  float* prob   = (float*)(w + 5132288);         // 128 f32 = 512 B
  int*   chainA = (int*)  (w + 5132800);         // 2048 int = 8192 B
  int*   chainB = (int*)  (w + 5140992);         // 2048 int = 8192 B

  k_init<<<1, 256, 0, stream>>>(loc_tar, chainA);

  int N = BB;
  int* cur = chainA;
  int* nxt = chainB;
  for (int i = 0; i < TT - 1; ++i) {
    int Mshift = (i == 0) ? 0 : ((i == 1) ? 2 : 3);
    dim3 g1(NTILE, (N + RPB - 1) / RPB);
    k_gemm<<<g1, 256, 0, stream>>>(E, zs, Wv, bv, cur, Lg, i, N, Mshift);
    k_red<<<N, 256, 0, stream>>>(Lg, topP, topI);
    k_beam<<<1, 512, 0, stream>>>(topP, topI, prob, cur, nxt, i);
    int* t2 = cur; cur = nxt; nxt = t2;
    N = (i == 0) ? BB * KK : BB * 2 * KK;
  }

  k_final<<<BB * (TT - 2), 64, 0, stream>>>(cur, E, Wc, bc, Wt, zt, Wzt, out);
}

// Round 13
// 1315.764 us; speedup vs baseline: 5.7394x; 1.0416x over previous
//
#include <hip/hip_runtime.h>
#include <math.h>

#define BB 16
#define TT 16
#define KK 4
#define VV 10003
#define DD 256
#define CC 64
#define NTILE 40        // ceil(V/256) v-tiles
#define RPB 16          // rows per k_gemm block
#define VP 10016        // padded row stride for logits scratch
#define FNEG (-1e30f)

// ---------- top-4 list, f32 keys (tie-break: lower index wins) ----------
struct L4 { float v[4]; int ix[4]; };

__device__ __forceinline__ void l4_init(L4 &l) {
#pragma unroll
  for (int j = 0; j < 4; ++j) { l.v[j] = FNEG; l.ix[j] = 0x7fffffff; }
}
__device__ __forceinline__ bool better(float v, int ix, float v2, int ix2) {
  return (v > v2) || (v == v2 && ix < ix2);
}
__device__ __forceinline__ void l4_insert(L4 &l, float v, int ix) {
  if (!better(v, ix, l.v[3], l.ix[3])) return;
  int p = 3;
  while (p > 0 && better(v, ix, l.v[p-1], l.ix[p-1])) {
    l.v[p] = l.v[p-1]; l.ix[p] = l.ix[p-1]; --p;
  }
  l.v[p] = v; l.ix[p] = ix;
}
__device__ __forceinline__ void l4_merge(L4 &a, const L4 &b) {
  L4 r; int ia = 0, ib = 0;
#pragma unroll
  for (int j = 0; j < 4; ++j) {
    if (better(a.v[ia], a.ix[ia], b.v[ib], b.ix[ib])) {
      r.v[j] = a.v[ia]; r.ix[j] = a.ix[ia]; ++ia;
    } else {
      r.v[j] = b.v[ib]; r.ix[j] = b.ix[ib]; ++ib;
    }
  }
  a = r;
}

// ---------- numpy pairwise_sum base case (8 <= n <= 128) — bit-exact ----------
__device__ float np_block_sum(const float* a, int n) {
  float r0=a[0],r1=a[1],r2=a[2],r3=a[3],r4=a[4],r5=a[5],r6=a[6],r7=a[7];
  int i;
  for (i = 8; i + 8 <= n; i += 8) {
    r0 += a[i+0]; r1 += a[i+1]; r2 += a[i+2]; r3 += a[i+3];
    r4 += a[i+4]; r5 += a[i+5]; r6 += a[i+6]; r7 += a[i+7];
  }
  float res = ((r0 + r1) + (r2 + r3)) + ((r4 + r5) + (r6 + r7));
  for (; i < n; ++i) res += a[i];
  return res;
}

// ---------- kernel 0: init chain ----------
__global__ void k_init(const int* __restrict__ loc_tar, int* __restrict__ chainA) {
  int t = threadIdx.x;            // 256 = B*T
  int b = t >> 4, j = t & 15;
  chainA[t] = (j == 0) ? loc_tar[b * TT] : 0;
}

// ---------- kernel 1: sgemm-mimic logits, register-direct Wv loads -----------
// Wv staging via LDS removed: each thread's W column was thread-private, so
// LDS bought nothing — load Wv straight to registers (coalesced), zero
// barriers in the d-loop. 1-D tile-major grid: 40 % 8 == 0 so tile == blk % 40
// keeps each v-tile on one XCD (round-robin dispatch) -> Wv slice (1.25 MB)
// stays L2-resident across all 15 steps. Arithmetic identical to R7-R12:
// one f32 acc per (row,col), fmaf chain in strictly ascending d.
__global__ __launch_bounds__(256)
void k_gemm(const float* __restrict__ E, const float* __restrict__ zs,
            const float* __restrict__ Wv, const float* __restrict__ bv,
            const int* __restrict__ chain, float* __restrict__ Lg,
            int step, int N, int Mshift) {
  __shared__ float xs[RPB * DD];     // 16 KB  (h rows, broadcast-read)
  __shared__ int cs[RPB];

  const int t = threadIdx.x;
  const int tile = blockIdx.x % NTILE;        // tile-major => XCD affinity
  const int n0 = (blockIdx.x / NTILE) * RPB;
  const int v0 = tile * 256;
  const int v = v0 + t;
  const int vok = (v < VV);
  const int vc = vok ? v : (VV - 1);

  if (t < RPB) {
    int n = n0 + t;
    int c = (n < N) ? chain[n * TT + step] : 0;
    if ((unsigned)c >= VV) c = 0;    // defensive
    cs[t] = c;
  }
  __syncthreads();

  // stage xs rows: h = E[c] + zs[b]  (single f32 add, np order)
  for (int e = t; e < RPB * DD; e += 256) {
    int r = e >> 8, d = e & 255;
    int n = n0 + r;
    int b = (n < N) ? (n >> Mshift) : 0;
    xs[e] = E[cs[r] * DD + d] + zs[b * DD + d];
  }
  __syncthreads();

  float acc[RPB];
#pragma unroll
  for (int r = 0; r < RPB; ++r) acc[r] = 0.f;

  const float* wp = Wv + vc;
  // d-loop: unroll 8 -> 8 independent global loads pipeline per group;
  // fmaf chains remain strictly d-ascending per accumulator (bit-exact).
  for (int d0 = 0; d0 < DD; d0 += 8) {
    float w[8];
#pragma unroll
    for (int u = 0; u < 8; ++u) w[u] = wp[(size_t)(d0 + u) * VV];
#pragma unroll
    for (int u = 0; u < 8; ++u) {
      const int d = d0 + u;
#pragma unroll
      for (int r = 0; r < RPB; ++r) acc[r] = fmaf(xs[r * DD + d], w[u], acc[r]);
    }
  }

  if (vok) {
    const float bvv = bv[v];
#pragma unroll
    for (int r = 0; r < RPB; ++r) {
      int n = n0 + r;
      if (n < N) Lg[(size_t)n * VP + v] = acc[r] + bvv;   // bias after gemm (np)
    }
  }
}

// ---------- kernel 2: np-exact max/top4/pairwise-lse, parallel (UNCHANGED) ----
__global__ __launch_bounds__(256)
void k_red(const float* __restrict__ Lg, float* __restrict__ topP,
           int* __restrict__ topI) {
  __shared__ float row[VV];          // 40012 B (logits, then exp'd values)
  __shared__ float pm[256];
  __shared__ float pv4[256 * 4];
  __shared__ int   pi4[256 * 4];
  __shared__ int   segBase[255];     // heap: node -> segment start
  __shared__ int   segN[255];        // heap: node -> segment size
  __shared__ float val[255];         // heap: node -> pairwise sum

  const int n = blockIdx.x;
  const int t = threadIdx.x;
  const float* grow = Lg + (size_t)n * VP;

  for (int v = t; v < VV; v += 256) row[v] = grow[v];

  if (t == 0) { segBase[0] = 0; segN[0] = VV; }
  __syncthreads();
  for (int L = 0; L < 7; ++L) {
    int first = (1 << L) - 1, cnt = 1 << L;
    if (t < cnt) {
      int p = first + t;
      int np_ = segN[p], bp = segBase[p];
      int n2 = np_ / 2; n2 -= n2 % 8;
      segBase[2 * p + 1] = bp;       segN[2 * p + 1] = n2;
      segBase[2 * p + 2] = bp + n2;  segN[2 * p + 2] = np_ - n2;
    }
    __syncthreads();
  }

  float m = FNEG;
  L4 top; l4_init(top);
  for (int v = t; v < VV; v += 256) {
    float x = row[v];
    if (x > m) m = x;
    l4_insert(top, x, v);
  }
  pm[t] = m;
#pragma unroll
  for (int j = 0; j < 4; ++j) { pv4[t * 4 + j] = top.v[j]; pi4[t * 4 + j] = top.ix[j]; }
  __syncthreads();

  for (int str = 128; str >= 1; str >>= 1) {
    if (t < str) {
      if (pm[t + str] > pm[t]) pm[t] = pm[t + str];
      L4 a, b;
#pragma unroll
      for (int j = 0; j < 4; ++j) {
        a.v[j] = pv4[t * 4 + j];          a.ix[j] = pi4[t * 4 + j];
        b.v[j] = pv4[(t + str) * 4 + j];  b.ix[j] = pi4[(t + str) * 4 + j];
      }
      l4_merge(a, b);
#pragma unroll
      for (int j = 0; j < 4; ++j) { pv4[t * 4 + j] = a.v[j]; pi4[t * 4 + j] = a.ix[j]; }
    }
    __syncthreads();
  }
  const float gm = pm[0];

  for (int v = t; v < VV; v += 256)
    row[v] = (float)exp((double)(row[v] - gm));
  __syncthreads();

  if (t < 128) {
    int nd = 127 + t;
    val[nd] = np_block_sum(&row[segBase[nd]], segN[nd]);
  }
  __syncthreads();

  for (int L = 6; L >= 0; --L) {
    int first = (1 << L) - 1, cnt = 1 << L;
    if (t < cnt) {
      int p = first + t;
      val[p] = val[2 * p + 1] + val[2 * p + 2];
    }
    __syncthreads();
  }

  if (t == 0) {
    float ls = (float)log((double)val[0]);
#pragma unroll
    for (int j = 0; j < 4; ++j) {
      topP[n * 4 + j] = (pv4[j] - gm) - ls;   // (x - m) - log(s), two f32 subs
      topI[n * 4 + j] = pi4[j];
    }
  }
}

// ---------- kernel 3: beam update, wave-parallel (UNCHANGED) ----------
__global__ __launch_bounds__(512)
void k_beam(const float* __restrict__ topP, const int* __restrict__ topI,
            float* __restrict__ prob, const int* __restrict__ chain_cur,
            int* __restrict__ chain_next, int step) {
  __shared__ int sel_src[BB][8];
  __shared__ int sel_tok[BB][8];

  const int tid = threadIdx.x;
  const int b = tid >> 5;      // batch 0..15
  const int c = tid & 31;      // candidate 0..31

  if (step == 0) {
    for (int e = tid; e < BB * KK * TT; e += 512) {
      int dst = e >> 4, q = e & 15;
      int bb = dst >> 2, kk = dst & 3;
      int val;
      if (q == 1) {
        int tok = topI[bb * 4 + kk]; if ((unsigned)tok >= VV) tok = 0;
        val = tok;
      } else {
        val = chain_cur[bb * TT + q];
      }
      chain_next[dst * TT + q] = val;
    }
    if (tid < BB * KK) {
      int bb = tid >> 2, kk = tid & 3;
      prob[bb * 8 + kk] = topP[bb * 4 + kk];
    }
    return;
  }

  const int M = (step == 1) ? 4 : 8;
  const int nc = M * 4;

  float act;
  if (c < nc) {
    int m = c >> 2, k = c & 3;
    act = prob[b * 8 + m] * topP[(b * M + m) * 4 + k];
  } else {
    act = -INFINITY;
  }

  for (int j = 0; j < 8; ++j) {
    float rv = act; int ri = c;
#pragma unroll
    for (int off = 1; off < 32; off <<= 1) {
      float v2 = __shfl_xor(rv, off, 32);
      int   i2 = __shfl_xor(ri, off, 32);
      if (v2 > rv || (v2 == rv && i2 < ri)) { rv = v2; ri = i2; }
    }
    if (c == ri) act = -INFINITY;          // mark used
    if (c == 0) {
      int m = ri >> 2, k = ri & 3;
      int src = b * M + m;
      int tok = topI[src * 4 + k]; if ((unsigned)tok >= VV) tok = 0;
      sel_src[b][j] = src;
      sel_tok[b][j] = tok;
      prob[b * 8 + j] = rv;
    }
  }
  __syncthreads();

  for (int e = tid; e < BB * 8 * TT; e += 512) {
    int dst = e >> 4, q = e & 15;
    int bb = dst >> 3, j = dst & 7;
    int src = sel_src[bb][j];
    int val = (q == step + 1) ? sel_tok[bb][j] : chain_cur[src * TT + q];
    chain_next[dst * TT + q] = val;
  }
}

// ---------- kernel 4: finalize: loc_chain + tim_chain (UNCHANGED) ----------
__global__ __launch_bounds__(64)
void k_final(const int* __restrict__ chain, const float* __restrict__ E,
             const float* __restrict__ Wc, const float* __restrict__ bc,
             const float* __restrict__ Wt, const float* __restrict__ zt,
             const float* __restrict__ Wzt, float* __restrict__ out) {
  int blk = blockIdx.x;           // 224 = B*(T-2)
  int b = blk / (TT - 2), t = blk % (TT - 2);
  int lane = threadIdx.x;         // 64 = C
  int loc = chain[(b * 8) * TT + 1 + t];   // best beam, positions 1..T-2
  if ((unsigned)loc >= VV) loc = 0;        // defensive
  double acc = (double)bc[lane];
  const float* er = E + loc * DD;
  for (int d = 0; d < DD; ++d) acc += (double)er[d] * (double)Wc[d * CC + lane];
  double val = tanh(acc) * (double)Wt[lane];
  const float* ztr = zt + b * DD;
#pragma unroll
  for (int q = 0; q < 4; ++q) val += (double)ztr[lane * 4 + q] * (double)Wzt[lane * 4 + q];
  for (int off = 32; off; off >>= 1) val += __shfl_down(val, off);
  if (lane == 0) {
    out[b * (TT - 2) + t] = (float)loc;                 // loc_chain as float
    out[BB * (TT - 2) + b * (TT - 2) + t] = (float)val; // tim_chain
  }
}

// ---------- host ----------
extern "C" void kernel_launch(void* const* d_in, const int* in_sizes, int n_in,
                              void* d_out, int out_size, void* d_ws, size_t ws_size,
                              hipStream_t stream) {
  const int*   loc_tar = (const int*)  d_in[0];
  const float* zs      = (const float*)d_in[1];
  const float* zt      = (const float*)d_in[2];
  const float* E       = (const float*)d_in[3];
  const float* Wv      = (const float*)d_in[4];
  const float* bv      = (const float*)d_in[5];
  const float* Wc      = (const float*)d_in[6];
  const float* bc      = (const float*)d_in[7];
  const float* Wt      = (const float*)d_in[8];
  const float* Wzt     = (const float*)d_in[9];
  float* out = (float*)d_out;

  char* w = (char*)d_ws;
  float* Lg     = (float*)(w);                   // 128*10016*4 = 5,128,192 B
  float* topP   = (float*)(w + 5128192);         // 512 f32 = 2048 B
  int*   topI   = (int*)  (w + 5130240);         // 512 int = 2048 B
  float* prob   = (float*)(w + 5132288);         // 128 f32 = 512 B
  int*   chainA = (int*)  (w + 5132800);         // 2048 int = 8192 B
  int*   chainB = (int*)  (w + 5140992);         // 2048 int = 8192 B

  k_init<<<1, 256, 0, stream>>>(loc_tar, chainA);

  int N = BB;
  int* cur = chainA;
  int* nxt = chainB;
  for (int i = 0; i < TT - 1; ++i) {
    int Mshift = (i == 0) ? 0 : ((i == 1) ? 2 : 3);
    int ntn = (N + RPB - 1) / RPB;
    k_gemm<<<ntn * NTILE, 256, 0, stream>>>(E, zs, Wv, bv, cur, Lg, i, N, Mshift);
    k_red<<<N, 256, 0, stream>>>(Lg, topP, topI);
    k_beam<<<1, 512, 0, stream>>>(topP, topI, prob, cur, nxt, i);
    int* t2 = cur; cur = nxt; nxt = t2;
    N = (i == 0) ? BB * KK : BB * 2 * KK;
  }

  k_final<<<BB * (TT - 2), 64, 0, stream>>>(cur, E, Wc, bc, Wt, zt, Wzt, out);
}